// Round 1
// baseline (23045.517 us; speedup 1.0000x reference)
//
#include <hip/hip_runtime.h>
#include <float.h>
#include <math.h>

#define NB 100000
#define SEQ 37
#define NTOK 1184  // 32*37

// ===================== sims: (32,768) @ bank(100000,768)^T =====================
// Per half-wave (32 lanes): 2 bank rows, lanes split k (float4). acc[b] per lane,
// then transpose-butterfly so lane kl ends with the full dot for batch row kl.
__device__ __forceinline__ float txreduce32(float a[32], int kl) {
#pragma unroll
  for (int m = 16; m >= 1; m >>= 1) {
    const bool hi = (kl & m) != 0;
#pragma unroll
    for (int i = 0; i < m; ++i) {
      float send = hi ? a[i] : a[i + m];
      float recv = __shfl_xor(send, m);
      a[i] = (hi ? a[i + m] : a[i]) + recv;
    }
  }
  return a[0];
}

__global__ __launch_bounds__(256) void sims_kernel(const float* __restrict__ cur,
                                                   const float* __restrict__ bank,
                                                   float* __restrict__ sims) {
  __shared__ float cs[32 * 384];
  const int tid = threadIdx.x;
  const int wid = tid >> 6;
  const int lane = tid & 63;
  const int half = lane >> 5;
  const int kl = lane & 31;
  for (int chunk = 0; chunk < 2; ++chunk) {
    __syncthreads();
    for (int i = tid; i < 32 * 384; i += 256) {
      int bb = i / 384, j = i - bb * 384;
      cs[i] = cur[bb * 768 + chunk * 384 + j];
    }
    __syncthreads();
    for (int tile = blockIdx.x; tile < NB / 16; tile += gridDim.x) {
      const int n0 = tile * 16 + wid * 4 + half * 2;
      const float* bp0 = bank + (size_t)n0 * 768 + chunk * 384;
      const float* bp1 = bp0 + 768;
      float acc0[32], acc1[32];
#pragma unroll
      for (int bb = 0; bb < 32; ++bb) { acc0[bb] = 0.f; acc1[bb] = 0.f; }
#pragma unroll
      for (int kk = 0; kk < 3; ++kk) {
        const int jo = kl * 4 + kk * 128;
        const float4 b0 = *(const float4*)(bp0 + jo);
        const float4 b1 = *(const float4*)(bp1 + jo);
#pragma unroll
        for (int bb = 0; bb < 32; ++bb) {
          const float4 c = *(const float4*)(cs + bb * 384 + jo);
          acc0[bb] += b0.x * c.x + b0.y * c.y + b0.z * c.z + b0.w * c.w;
          acc1[bb] += b1.x * c.x + b1.y * c.y + b1.z * c.z + b1.w * c.w;
        }
      }
      float t0 = txreduce32(acc0, kl);
      float t1 = txreduce32(acc1, kl);
      size_t o = (size_t)kl * NB + n0;
      if (chunk == 0) { sims[o] = t0; sims[o + 1] = t1; }
      else            { sims[o] += t0; sims[o + 1] += t1; }
    }
  }
}

// ===================== top-K (K=16) per batch row, ties -> lower index ==========
__global__ __launch_bounds__(256) void topk_kernel(const float* __restrict__ sims,
                                                   float* __restrict__ tks,
                                                   int* __restrict__ tki) {
  __shared__ float ss[4096];
  __shared__ int si[4096];
  __shared__ float wv[4];
  __shared__ int wi[4];
  const int b = blockIdx.x, tid = threadIdx.x;
  float ls[16]; int li[16];
#pragma unroll
  for (int i = 0; i < 16; ++i) { ls[i] = -FLT_MAX; li[i] = 0x7fffffff; }
  const float* row = sims + (size_t)b * NB;
  float lmin = -FLT_MAX;
  for (int n = tid; n < NB; n += 256) {
    float v = row[n];
    if (v > lmin) {  // strict > keeps earlier (lower) index on ties
      int p = 15;
      while (p > 0 && ls[p - 1] < v) { ls[p] = ls[p - 1]; li[p] = li[p - 1]; --p; }
      ls[p] = v; li[p] = n;
      lmin = ls[15];
    }
  }
#pragma unroll
  for (int i = 0; i < 16; ++i) { ss[i * 256 + tid] = ls[i]; si[i * 256 + tid] = li[i]; }
  __syncthreads();
  for (int round = 0; round < 16; ++round) {
    float bv = -FLT_MAX; int bi = 0x7fffffff;
#pragma unroll
    for (int i = 0; i < 16; ++i) {
      float v = ss[i * 256 + tid]; int ix = si[i * 256 + tid];
      if (v > bv || (v == bv && ix < bi)) { bv = v; bi = ix; }
    }
#pragma unroll
    for (int s = 32; s; s >>= 1) {
      float ov = __shfl_down(bv, s); int oi = __shfl_down(bi, s);
      if (ov > bv || (ov == bv && oi < bi)) { bv = ov; bi = oi; }
    }
    if ((tid & 63) == 0) { wv[tid >> 6] = bv; wi[tid >> 6] = bi; }
    __syncthreads();
    if (tid == 0) {
      bv = wv[0]; bi = wi[0];
      for (int w = 1; w < 4; ++w)
        if (wv[w] > bv || (wv[w] == bv && wi[w] < bi)) { bv = wv[w]; bi = wi[w]; }
      tks[b * 16 + round] = bv; tki[b * 16 + round] = bi;
      wi[0] = bi;
    }
    __syncthreads();
    bi = wi[0];
#pragma unroll
    for (int i = 0; i < 16; ++i)
      if (si[i * 256 + tid] == bi) ss[i * 256 + tid] = -FLT_MAX;
    __syncthreads();
  }
}

// ===================== small copy/assembly kernels ==============================
__global__ void sem_kernel(const float* __restrict__ bank, const float* __restrict__ tks,
                           const int* __restrict__ tki, float* __restrict__ sem) {
  int slot = blockIdx.x;  // b*16 + j
  float s = tks[slot]; int idx = tki[slot];
  for (int i = threadIdx.x; i < 768; i += 256)
    sem[(size_t)slot * 768 + i] = bank[(size_t)idx * 768 + i] * s;
}

__global__ void build_hist_in(const float* __restrict__ img, const float* __restrict__ pr,
                              float* __restrict__ out) {
  int r = blockIdx.x;  // b*16 + t
  for (int i = threadIdx.x; i < 777; i += 256)
    out[(size_t)r * 777 + i] = (i < 768) ? img[(size_t)r * 768 + i] : pr[r * 9 + (i - 768)];
}

__global__ void build_img_in(const float* __restrict__ goal, const float* __restrict__ sub,
                             const float* __restrict__ bea, const float* __restrict__ sem,
                             float* __restrict__ out) {
  int r = blockIdx.x;  // 0..607
  const float* src = (r < 32) ? goal + (size_t)r * 768
                   : (r < 64) ? sub + (size_t)(r - 32) * 768
                   : (r < 96) ? bea + (size_t)(r - 64) * 768
                              : sem + (size_t)(r - 96) * 768;
  for (int i = threadIdx.x; i < 768; i += 256) out[(size_t)r * 768 + i] = src[i];
}

__global__ void assemble_x(const float* __restrict__ th, const float* __restrict__ ti,
                           const float* __restrict__ tp, const float* __restrict__ plan,
                           float* __restrict__ x) {
  int r = blockIdx.x;           // b*37 + tok
  int b = r / SEQ, tok = r - b * SEQ;
  const float* src;
  if (tok == 0) src = plan;
  else if (tok <= 16) src = th + (size_t)(b * 16 + tok - 1) * 1024;
  else if (tok <= 19) src = ti + (size_t)((tok - 17) * 32 + b) * 1024;
  else if (tok <= 35) src = ti + (size_t)(96 + b * 16 + (tok - 20)) * 1024;
  else src = tp + (size_t)b * 1024;
  for (int i = threadIdx.x; i < 1024; i += 256) x[(size_t)r * 1024 + i] = src[i];
}

__global__ void build_ref(const float* __restrict__ ps, const float* __restrict__ anc,
                          float* __restrict__ ref) {
  int b = blockIdx.x;
  for (int i = threadIdx.x; i < 1027; i += 256)
    ref[(size_t)b * 1027 + i] = (i < 1024) ? ps[(size_t)b * 1024 + i] : anc[b * 3 + (i - 1024)];
}

// ===================== layernorm (two-pass, matches reference) ==================
__device__ __forceinline__ float block_sum256(float v, float* red) {
#pragma unroll
  for (int s = 32; s; s >>= 1) v += __shfl_down(v, s);
  if ((threadIdx.x & 63) == 0) red[threadIdx.x >> 6] = v;
  __syncthreads();
  float tot = red[0] + red[1] + red[2] + red[3];
  __syncthreads();
  return tot;
}

__global__ __launch_bounds__(256) void ln_kernel(const float* __restrict__ in, int in_stride,
                                                 float* __restrict__ out,
                                                 const float* __restrict__ g,
                                                 const float* __restrict__ bt) {
  __shared__ float red[4];
  const float* xr = in + (size_t)blockIdx.x * in_stride;
  const int tid = threadIdx.x;
  float v[4];
#pragma unroll
  for (int i = 0; i < 4; ++i) v[i] = xr[tid + 256 * i];
  float mean = block_sum256(v[0] + v[1] + v[2] + v[3], red) * (1.f / 1024.f);
  float sq = 0.f;
#pragma unroll
  for (int i = 0; i < 4; ++i) { float d = v[i] - mean; sq += d * d; }
  float var = block_sum256(sq, red) * (1.f / 1024.f);
  float inv = rsqrtf(var + 1e-5f);
  float* orow = out + (size_t)blockIdx.x * 1024;
#pragma unroll
  for (int i = 0; i < 4; ++i) {
    int c = tid + 256 * i;
    orow[c] = (v[i] - mean) * inv * g[c] + bt[c];
  }
}

// ===================== generic fp32 GEMM: C = A(M,K) @ W(N,K)^T + bias ==========
__global__ __launch_bounds__(256) void gemm_f32(const float* __restrict__ A, int lda,
                                                const float* __restrict__ W, int ldw,
                                                const float* __restrict__ bias,
                                                float* __restrict__ C, int ldc,
                                                int M, int N, int K, int acc_flag) {
  __shared__ float As[32][68];  // [k][m], +pad: float4 reads stay 16B aligned
  __shared__ float Ws[32][68];
  const int tid = threadIdx.x;
  const int tx = tid & 15, ty = tid >> 4;
  const int bm = blockIdx.x * 64, bn = blockIdx.y * 64;
  float acc[4][4] = {{0.f, 0.f, 0.f, 0.f}, {0.f, 0.f, 0.f, 0.f},
                     {0.f, 0.f, 0.f, 0.f}, {0.f, 0.f, 0.f, 0.f}};
  for (int kc = 0; kc < K; kc += 32) {
    for (int i = tid; i < 64 * 32; i += 256) {
      int r = i >> 5, kk = i & 31;
      int gk = kc + kk;
      int gm = bm + r, gn = bn + r;
      As[kk][r] = (gm < M && gk < K) ? A[(size_t)gm * lda + gk] : 0.f;
      Ws[kk][r] = (gn < N && gk < K) ? W[(size_t)gn * ldw + gk] : 0.f;
    }
    __syncthreads();
#pragma unroll
    for (int kk = 0; kk < 32; ++kk) {
      float4 av = *(const float4*)&As[kk][ty * 4];
      float4 bv = *(const float4*)&Ws[kk][tx * 4];
      float a4[4] = {av.x, av.y, av.z, av.w};
      float b4[4] = {bv.x, bv.y, bv.z, bv.w};
#pragma unroll
      for (int i = 0; i < 4; ++i)
#pragma unroll
        for (int j = 0; j < 4; ++j) acc[i][j] += a4[i] * b4[j];
    }
    __syncthreads();
  }
#pragma unroll
  for (int i = 0; i < 4; ++i) {
    int gm = bm + ty * 4 + i;
    if (gm >= M) continue;
#pragma unroll
    for (int j = 0; j < 4; ++j) {
      int gn = bn + tx * 4 + j;
      if (gn >= N) continue;
      float o = acc[i][j] + bias[gn];
      size_t off = (size_t)gm * ldc + gn;
      if (acc_flag) o += C[off];
      C[off] = o;
    }
  }
}

// ===================== LoRA =====================================================
__global__ __launch_bounds__(64) void lora_down(const float* __restrict__ h,
                                                const float* __restrict__ A,
                                                float* __restrict__ lt, int K) {
  const int m = blockIdx.x, lane = threadIdx.x;
  float p[8] = {0.f, 0.f, 0.f, 0.f, 0.f, 0.f, 0.f, 0.f};
  for (int kk = lane; kk < K; kk += 64) {
    float hv = h[(size_t)m * K + kk];
#pragma unroll
    for (int r = 0; r < 8; ++r) p[r] += hv * A[r * K + kk];
  }
#pragma unroll
  for (int s = 1; s < 64; s <<= 1) {
#pragma unroll
    for (int r = 0; r < 8; ++r) p[r] += __shfl_xor(p[r], s);
  }
#pragma unroll
  for (int r = 0; r < 8; ++r)
    if (lane == r) lt[m * 8 + r] = p[r];
}

__global__ __launch_bounds__(256) void lora_up(const float* __restrict__ lt,
                                               const float* __restrict__ Bm,
                                               float* __restrict__ C, int N, int total) {
  int id = blockIdx.x * 256 + threadIdx.x;
  if (id >= total) return;
  int m = id / N, n = id - m * N;
  const float* t = lt + (size_t)m * 8;
  const float* bp = Bm + (size_t)n * 8;
  float s = t[0] * bp[0] + t[1] * bp[1] + t[2] * bp[2] + t[3] * bp[3] +
            t[4] * bp[4] + t[5] * bp[5] + t[6] * bp[6] + t[7] * bp[7];
  C[id] += s;
}

// ===================== attention: one block per (head, batch) ===================
__global__ __launch_bounds__(256) void attn_kernel(const float* __restrict__ q,
                                                   const float* __restrict__ k,
                                                   const float* __restrict__ v,
                                                   float* __restrict__ ao) {
  __shared__ float qs[SEQ * 64], ks[SEQ * 64], vs[SEQ * 64], sc[SEQ * 40];
  const int head = blockIdx.x, b = blockIdx.y, tid = threadIdx.x;
  const size_t base = ((size_t)b * SEQ) * 1024 + head * 64;
  for (int i = tid; i < SEQ * 64; i += 256) {
    int s = i >> 6, d = i & 63;
    size_t off = base + (size_t)s * 1024 + d;
    qs[i] = q[off]; ks[i] = k[off]; vs[i] = v[off];
  }
  __syncthreads();
  for (int p = tid; p < SEQ * SEQ; p += 256) {
    int s = p / SEQ, t = p - s * SEQ;
    float acc = 0.f;
#pragma unroll 16
    for (int d = 0; d < 64; ++d) acc += qs[s * 64 + d] * ks[t * 64 + d];
    sc[s * 40 + t] = acc * 0.125f;  // 1/sqrt(64)
  }
  __syncthreads();
  if (tid < SEQ) {
    float m = -FLT_MAX;
    for (int t = 0; t < SEQ; ++t) m = fmaxf(m, sc[tid * 40 + t]);
    float sum = 0.f;
    for (int t = 0; t < SEQ; ++t) { float e = expf(sc[tid * 40 + t] - m); sc[tid * 40 + t] = e; sum += e; }
    float inv = 1.f / sum;
    for (int t = 0; t < SEQ; ++t) sc[tid * 40 + t] *= inv;
  }
  __syncthreads();
  for (int i = tid; i < SEQ * 64; i += 256) {
    int s = i >> 6, d = i & 63;
    float acc = 0.f;
    for (int t = 0; t < SEQ; ++t) acc += sc[s * 40 + t] * vs[t * 64 + d];
    ao[base + (size_t)s * 1024 + d] = acc;
  }
}

// ===================== gelu (exact, erf) ========================================
__global__ void gelu_kernel(float* __restrict__ x, int n) {
  int i = blockIdx.x * blockDim.x + threadIdx.x;
  if (i < n) {
    float v = x[i];
    x[i] = 0.5f * v * (1.f + erff(v * 0.70710678118654752f));
  }
}

// ===================== host =====================================================
extern "C" void kernel_launch(void* const* d_in, const int* in_sizes, int n_in,
                              void* d_out, int out_size, void* d_ws, size_t ws_size,
                              hipStream_t stream) {
  const float* hist_img = (const float*)d_in[0];
  const float* cur      = (const float*)d_in[1];
  const float* goal     = (const float*)d_in[2];
  const float* sub      = (const float*)d_in[3];
  const float* bea      = (const float*)d_in[4];
  const float* hist_pr  = (const float*)d_in[5];
  const float* prop     = (const float*)d_in[6];
  const float* bank     = (const float*)d_in[7];
  const float* hpW = (const float*)d_in[8];  const float* hpb = (const float*)d_in[9];
  const float* ipW = (const float*)d_in[10]; const float* ipb = (const float*)d_in[11];
  const float* ppW = (const float*)d_in[12]; const float* ppb = (const float*)d_in[13];
  const float* plan = (const float*)d_in[14];
  const float* ln1g = (const float*)d_in[15]; const float* ln1b = (const float*)d_in[16];
  const float* ln2g = (const float*)d_in[17]; const float* ln2b = (const float*)d_in[18];
  const float* qW = (const float*)d_in[19]; const float* qA = (const float*)d_in[20];
  const float* qB = (const float*)d_in[21]; const float* qb = (const float*)d_in[22];
  const float* kW = (const float*)d_in[23]; const float* kA = (const float*)d_in[24];
  const float* kB = (const float*)d_in[25]; const float* kb = (const float*)d_in[26];
  const float* vW = (const float*)d_in[27]; const float* vA = (const float*)d_in[28];
  const float* vB = (const float*)d_in[29]; const float* vb = (const float*)d_in[30];
  const float* oW = (const float*)d_in[31]; const float* oA = (const float*)d_in[32];
  const float* oB = (const float*)d_in[33]; const float* ob = (const float*)d_in[34];
  const float* f1W = (const float*)d_in[35]; const float* f1A = (const float*)d_in[36];
  const float* f1B = (const float*)d_in[37]; const float* f1b = (const float*)d_in[38];
  const float* f2W = (const float*)d_in[39]; const float* f2A = (const float*)d_in[40];
  const float* f2B = (const float*)d_in[41]; const float* f2b = (const float*)d_in[42];
  const float* flng = (const float*)d_in[43]; const float* flnb = (const float*)d_in[44];
  const float* ahW1 = (const float*)d_in[45]; const float* ahb1 = (const float*)d_in[46];
  const float* ahW2 = (const float*)d_in[47]; const float* ahb2 = (const float*)d_in[48];
  const float* rhW1 = (const float*)d_in[49]; const float* rhb1 = (const float*)d_in[50];
  const float* rhW2 = (const float*)d_in[51]; const float* rhb2 = (const float*)d_in[52];
  const float* shW = (const float*)d_in[53]; const float* shb = (const float*)d_in[54];
  float* out = (float*)d_out;

  // workspace layout (floats), ~52.1 MB total
  float* ws  = (float*)d_ws;
  float* F1O = ws;                              // 1184*4096 (aliases SIMS)
  float* SIMS = ws;                             // 32*100000 <= 1184*4096
  float* X   = F1O + (size_t)NTOK * 4096;
  float* Hb  = X  + (size_t)NTOK * 1024;
  float* Qb  = Hb + (size_t)NTOK * 1024;        // also tmp_hist pre-layers
  float* Kb  = Qb + (size_t)NTOK * 1024;        // also tmp_img  pre-layers
  float* Vb  = Kb + (size_t)NTOK * 1024;        // also tmp_prop pre-layers
  float* AOb = Vb + (size_t)NTOK * 1024;        // also img_in   pre-layers
  float* LT  = AOb + (size_t)NTOK * 1024;       // 1184*8
  float* SEM = LT + (size_t)NTOK * 8;           // 512*768
  float* HIN = SEM + (size_t)512 * 768;         // 512*777
  float* TKS = HIN + (size_t)512 * 777;         // 512
  int*   TKI = (int*)(TKS + 512);               // 512
  float* PS  = TKS + 1024;                      // 32*1024
  float* HH  = PS + 32 * 1024;                  // 32*1024
  float* REF = HH + 32 * 1024;                  // 32*1027

  auto gemm = [&](const float* A, int lda, const float* W, int ldw, const float* bias,
                  float* C, int ldc, int M, int N, int K, int accf) {
    dim3 g((M + 63) / 64, (N + 63) / 64);
    gemm_f32<<<g, 256, 0, stream>>>(A, lda, W, ldw, bias, C, ldc, M, N, K, accf);
  };

  // ---- retrieval ----
  sims_kernel<<<1024, 256, 0, stream>>>(cur, bank, SIMS);
  topk_kernel<<<32, 256, 0, stream>>>(SIMS, TKS, TKI);
  sem_kernel<<<512, 256, 0, stream>>>(bank, TKS, TKI, SEM);

  // ---- token embedding ----
  build_hist_in<<<512, 256, 0, stream>>>(hist_img, hist_pr, HIN);
  build_img_in<<<608, 256, 0, stream>>>(goal, sub, bea, SEM, AOb);
  gemm(HIN, 777, hpW, 777, hpb, Qb, 1024, 512, 1024, 777, 0);   // hist -> Qb
  gemm(AOb, 768, ipW, 768, ipb, Kb, 1024, 608, 1024, 768, 0);   // img  -> Kb
  gemm(prop, 9, ppW, 9, ppb, Vb, 1024, 32, 1024, 9, 0);         // prop -> Vb
  assemble_x<<<NTOK, 256, 0, stream>>>(Qb, Kb, Vb, plan, X);

  // ---- transformer layers ----
  for (int l = 0; l < 6; ++l) {
    const size_t wO = (size_t)l * 1024 * 1024, aO = (size_t)l * 8 * 1024,
                 bO = (size_t)l * 1024 * 8, biO = (size_t)l * 1024;
    ln_kernel<<<NTOK, 256, 0, stream>>>(X, 1024, Hb, ln1g + biO, ln1b + biO);
    gemm(Hb, 1024, qW + wO, 1024, qb + biO, Qb, 1024, NTOK, 1024, 1024, 0);
    lora_down<<<NTOK, 64, 0, stream>>>(Hb, qA + aO, LT, 1024);
    lora_up<<<(NTOK * 1024 + 255) / 256, 256, 0, stream>>>(LT, qB + bO, Qb, 1024, NTOK * 1024);
    gemm(Hb, 1024, kW + wO, 1024, kb + biO, Kb, 1024, NTOK, 1024, 1024, 0);
    lora_down<<<NTOK, 64, 0, stream>>>(Hb, kA + aO, LT, 1024);
    lora_up<<<(NTOK * 1024 + 255) / 256, 256, 0, stream>>>(LT, kB + bO, Kb, 1024, NTOK * 1024);
    gemm(Hb, 1024, vW + wO, 1024, vb + biO, Vb, 1024, NTOK, 1024, 1024, 0);
    lora_down<<<NTOK, 64, 0, stream>>>(Hb, vA + aO, LT, 1024);
    lora_up<<<(NTOK * 1024 + 255) / 256, 256, 0, stream>>>(LT, vB + bO, Vb, 1024, NTOK * 1024);
    attn_kernel<<<dim3(16, 32), 256, 0, stream>>>(Qb, Kb, Vb, AOb);
    gemm(AOb, 1024, oW + wO, 1024, ob + biO, X, 1024, NTOK, 1024, 1024, 1);
    lora_down<<<NTOK, 64, 0, stream>>>(AOb, oA + aO, LT, 1024);
    lora_up<<<(NTOK * 1024 + 255) / 256, 256, 0, stream>>>(LT, oB + bO, X, 1024, NTOK * 1024);
    ln_kernel<<<NTOK, 256, 0, stream>>>(X, 1024, Hb, ln2g + biO, ln2b + biO);
    const size_t w4O = (size_t)l * 4096 * 1024, a4O = (size_t)l * 8 * 4096,
                 b4O = (size_t)l * 4096 * 8, bi4O = (size_t)l * 4096;
    gemm(Hb, 1024, f1W + w4O, 1024, f1b + bi4O, F1O, 4096, NTOK, 4096, 1024, 0);
    lora_down<<<NTOK, 64, 0, stream>>>(Hb, f1A + aO, LT, 1024);
    lora_up<<<(NTOK * 4096 + 255) / 256, 256, 0, stream>>>(LT, f1B + b4O, F1O, 4096, NTOK * 4096);
    gelu_kernel<<<(NTOK * 4096 + 255) / 256, 256, 0, stream>>>(F1O, NTOK * 4096);
    gemm(F1O, 4096, f2W + w4O, 4096, f2b + biO, X, 1024, NTOK, 1024, 4096, 1);
    lora_down<<<NTOK, 64, 0, stream>>>(F1O, f2A + a4O, LT, 4096);
    lora_up<<<(NTOK * 1024 + 255) / 256, 256, 0, stream>>>(LT, f2B + bO, X, 1024, NTOK * 1024);
  }

  // ---- heads ----
  ln_kernel<<<32, 256, 0, stream>>>(X, SEQ * 1024, PS, flng, flnb);  // token 0 of each b
  gemm(PS, 1024, ahW1, 1024, ahb1, HH, 1024, 32, 1024, 1024, 0);
  gelu_kernel<<<(32 * 1024 + 255) / 256, 256, 0, stream>>>(HH, 32 * 1024);
  gemm(HH, 1024, ahW2, 1024, ahb2, out, 3, 32, 3, 1024, 0);          // anchor -> out[0:96]
  build_ref<<<32, 256, 0, stream>>>(PS, out, REF);
  gemm(REF, 1027, rhW1, 1027, rhb1, HH, 1024, 32, 1024, 1027, 0);
  gelu_kernel<<<(32 * 1024 + 255) / 256, 256, 0, stream>>>(HH, 32 * 1024);
  gemm(HH, 1024, rhW2, 1024, rhb2, out + 96, 24, 32, 24, 1024, 0);   // waypoints -> out[96:864]
  gemm(PS, 1024, shW, 1024, shb, out + 864, 1, 32, 1, 1024, 0);      // stop -> out[864:896]
}

// Round 2
// 12781.709 us; speedup vs baseline: 1.8030x; 1.8030x over previous
//
#include <hip/hip_runtime.h>
#include <float.h>
#include <math.h>

#define NB 100000
#define SEQ 37
#define NTOK 1184  // 32*37

// ============ sims: C(100000,32) = bank(100000,768) @ cur(32,768)^T ============
// Tiled fp32 GEMM. Tile: 128 bank rows x 32 batch, BK=32. LDS layout [k][row]
// (transpose on store, odd-ish stride pads -> <=2-way conflicts on store,
// conflict-free float4 reads). 4x4 register tile per thread. Memory-bound:
// floor = 307 MB / 6.3 TB/s ~= 49 us.
__global__ __launch_bounds__(256) void sims_kernel(const float* __restrict__ cur,
                                                   const float* __restrict__ bank,
                                                   float* __restrict__ sims) {
  __shared__ float Bs[32][132];  // [k][bank-row], stride 132: b128-read conflict-free
  __shared__ float Cs[32][36];   // [k][batch]
  const int tid = threadIdx.x;
  const int tx = tid & 7;        // batch-col group (0..7) -> cols tx*4..+3
  const int ty = tid >> 3;       // bank-row group (0..31) -> rows ty*4..+3
  const int n0 = blockIdx.x * 128;

  // staging indices
  const int srow = tid >> 1;       // 0..127
  const int spart = tid & 1;       // 0..1 (k half: 16 floats each)
  const int cb = tid >> 3;         // 0..31 batch row
  const int ck = (tid & 7) * 4;    // k offset 0..28

  float acc[4][4] = {{0.f,0.f,0.f,0.f},{0.f,0.f,0.f,0.f},
                     {0.f,0.f,0.f,0.f},{0.f,0.f,0.f,0.f}};

  const bool rok = (n0 + srow) < NB;
  const float* bp = bank + (size_t)(n0 + srow) * 768 + spart * 16;
  const float* cp = cur + (size_t)cb * 768 + ck;

  for (int kc = 0; kc < 768; kc += 32) {
    __syncthreads();
    // bank tile -> Bs (transpose). 4x float4 per thread = 16 floats.
#pragma unroll
    for (int jj = 0; jj < 4; ++jj) {
      float4 v = rok ? *(const float4*)(bp + kc + jj * 4)
                     : make_float4(0.f, 0.f, 0.f, 0.f);
      const int kk = spart * 16 + jj * 4;
      Bs[kk + 0][srow] = v.x; Bs[kk + 1][srow] = v.y;
      Bs[kk + 2][srow] = v.z; Bs[kk + 3][srow] = v.w;
    }
    // cur tile -> Cs (transpose). 1x float4 per thread.
    {
      float4 v = *(const float4*)(cp + kc);
      Cs[ck + 0][cb] = v.x; Cs[ck + 1][cb] = v.y;
      Cs[ck + 2][cb] = v.z; Cs[ck + 3][cb] = v.w;
    }
    __syncthreads();
#pragma unroll
    for (int kk = 0; kk < 32; ++kk) {
      float4 av = *(const float4*)&Bs[kk][ty * 4];
      float4 bv = *(const float4*)&Cs[kk][tx * 4];
      float a4[4] = {av.x, av.y, av.z, av.w};
      float b4[4] = {bv.x, bv.y, bv.z, bv.w};
#pragma unroll
      for (int i = 0; i < 4; ++i)
#pragma unroll
        for (int j = 0; j < 4; ++j) acc[i][j] += a4[i] * b4[j];
    }
  }
  const int n = n0 + ty * 4;
#pragma unroll
  for (int j = 0; j < 4; ++j) {
    const int b = tx * 4 + j;
    float4 o = make_float4(acc[0][j], acc[1][j], acc[2][j], acc[3][j]);
    if (n + 3 < NB) {
      *(float4*)(sims + (size_t)b * NB + n) = o;
    } else {
      float oo[4] = {o.x, o.y, o.z, o.w};
      for (int i = 0; i < 4; ++i)
        if (n + i < NB) sims[(size_t)b * NB + n + i] = oo[i];
    }
  }
}

// ===================== top-K (K=16) per batch row, ties -> lower index ==========
__global__ __launch_bounds__(256) void topk_kernel(const float* __restrict__ sims,
                                                   float* __restrict__ tks,
                                                   int* __restrict__ tki) {
  __shared__ float ss[4096];
  __shared__ int si[4096];
  __shared__ float wv[4];
  __shared__ int wi[4];
  const int b = blockIdx.x, tid = threadIdx.x;
  float ls[16]; int li[16];
#pragma unroll
  for (int i = 0; i < 16; ++i) { ls[i] = -FLT_MAX; li[i] = 0x7fffffff; }
  const float* row = sims + (size_t)b * NB;
  float lmin = -FLT_MAX;
  for (int n = tid; n < NB; n += 256) {
    float v = row[n];
    if (v > lmin) {  // strict > keeps earlier (lower) index on ties
      int p = 15;
      while (p > 0 && ls[p - 1] < v) { ls[p] = ls[p - 1]; li[p] = li[p - 1]; --p; }
      ls[p] = v; li[p] = n;
      lmin = ls[15];
    }
  }
#pragma unroll
  for (int i = 0; i < 16; ++i) { ss[i * 256 + tid] = ls[i]; si[i * 256 + tid] = li[i]; }
  __syncthreads();
  for (int round = 0; round < 16; ++round) {
    float bv = -FLT_MAX; int bi = 0x7fffffff;
#pragma unroll
    for (int i = 0; i < 16; ++i) {
      float v = ss[i * 256 + tid]; int ix = si[i * 256 + tid];
      if (v > bv || (v == bv && ix < bi)) { bv = v; bi = ix; }
    }
#pragma unroll
    for (int s = 32; s; s >>= 1) {
      float ov = __shfl_down(bv, s); int oi = __shfl_down(bi, s);
      if (ov > bv || (ov == bv && oi < bi)) { bv = ov; bi = oi; }
    }
    if ((tid & 63) == 0) { wv[tid >> 6] = bv; wi[tid >> 6] = bi; }
    __syncthreads();
    if (tid == 0) {
      bv = wv[0]; bi = wi[0];
      for (int w = 1; w < 4; ++w)
        if (wv[w] > bv || (wv[w] == bv && wi[w] < bi)) { bv = wv[w]; bi = wi[w]; }
      tks[b * 16 + round] = bv; tki[b * 16 + round] = bi;
      wi[0] = bi;
    }
    __syncthreads();
    bi = wi[0];
#pragma unroll
    for (int i = 0; i < 16; ++i)
      if (si[i * 256 + tid] == bi) ss[i * 256 + tid] = -FLT_MAX;
    __syncthreads();
  }
}

// ===================== small copy/assembly kernels ==============================
__global__ void sem_kernel(const float* __restrict__ bank, const float* __restrict__ tks,
                           const int* __restrict__ tki, float* __restrict__ sem) {
  int slot = blockIdx.x;  // b*16 + j
  float s = tks[slot]; int idx = tki[slot];
  for (int i = threadIdx.x; i < 768; i += 256)
    sem[(size_t)slot * 768 + i] = bank[(size_t)idx * 768 + i] * s;
}

__global__ void build_hist_in(const float* __restrict__ img, const float* __restrict__ pr,
                              float* __restrict__ out) {
  int r = blockIdx.x;  // b*16 + t
  for (int i = threadIdx.x; i < 777; i += 256)
    out[(size_t)r * 777 + i] = (i < 768) ? img[(size_t)r * 768 + i] : pr[r * 9 + (i - 768)];
}

__global__ void build_img_in(const float* __restrict__ goal, const float* __restrict__ sub,
                             const float* __restrict__ bea, const float* __restrict__ sem,
                             float* __restrict__ out) {
  int r = blockIdx.x;  // 0..607
  const float* src = (r < 32) ? goal + (size_t)r * 768
                   : (r < 64) ? sub + (size_t)(r - 32) * 768
                   : (r < 96) ? bea + (size_t)(r - 64) * 768
                              : sem + (size_t)(r - 96) * 768;
  for (int i = threadIdx.x; i < 768; i += 256) out[(size_t)r * 768 + i] = src[i];
}

__global__ void assemble_x(const float* __restrict__ th, const float* __restrict__ ti,
                           const float* __restrict__ tp, const float* __restrict__ plan,
                           float* __restrict__ x) {
  int r = blockIdx.x;           // b*37 + tok
  int b = r / SEQ, tok = r - b * SEQ;
  const float* src;
  if (tok == 0) src = plan;
  else if (tok <= 16) src = th + (size_t)(b * 16 + tok - 1) * 1024;
  else if (tok <= 19) src = ti + (size_t)((tok - 17) * 32 + b) * 1024;
  else if (tok <= 35) src = ti + (size_t)(96 + b * 16 + (tok - 20)) * 1024;
  else src = tp + (size_t)b * 1024;
  for (int i = threadIdx.x; i < 1024; i += 256) x[(size_t)r * 1024 + i] = src[i];
}

__global__ void build_ref(const float* __restrict__ ps, const float* __restrict__ anc,
                          float* __restrict__ ref) {
  int b = blockIdx.x;
  for (int i = threadIdx.x; i < 1027; i += 256)
    ref[(size_t)b * 1027 + i] = (i < 1024) ? ps[(size_t)b * 1024 + i] : anc[b * 3 + (i - 1024)];
}

// ===================== layernorm (two-pass, matches reference) ==================
__device__ __forceinline__ float block_sum256(float v, float* red) {
#pragma unroll
  for (int s = 32; s; s >>= 1) v += __shfl_down(v, s);
  if ((threadIdx.x & 63) == 0) red[threadIdx.x >> 6] = v;
  __syncthreads();
  float tot = red[0] + red[1] + red[2] + red[3];
  __syncthreads();
  return tot;
}

__global__ __launch_bounds__(256) void ln_kernel(const float* __restrict__ in, int in_stride,
                                                 float* __restrict__ out,
                                                 const float* __restrict__ g,
                                                 const float* __restrict__ bt) {
  __shared__ float red[4];
  const float* xr = in + (size_t)blockIdx.x * in_stride;
  const int tid = threadIdx.x;
  float v[4];
#pragma unroll
  for (int i = 0; i < 4; ++i) v[i] = xr[tid + 256 * i];
  float mean = block_sum256(v[0] + v[1] + v[2] + v[3], red) * (1.f / 1024.f);
  float sq = 0.f;
#pragma unroll
  for (int i = 0; i < 4; ++i) { float d = v[i] - mean; sq += d * d; }
  float var = block_sum256(sq, red) * (1.f / 1024.f);
  float inv = rsqrtf(var + 1e-5f);
  float* orow = out + (size_t)blockIdx.x * 1024;
#pragma unroll
  for (int i = 0; i < 4; ++i) {
    int c = tid + 256 * i;
    orow[c] = (v[i] - mean) * inv * g[c] + bt[c];
  }
}

// ===================== generic fp32 GEMM: C = A(M,K) @ W(N,K)^T + bias ==========
__global__ __launch_bounds__(256) void gemm_f32(const float* __restrict__ A, int lda,
                                                const float* __restrict__ W, int ldw,
                                                const float* __restrict__ bias,
                                                float* __restrict__ C, int ldc,
                                                int M, int N, int K, int acc_flag) {
  __shared__ float As[32][68];  // [k][m], +pad: float4 reads stay 16B aligned
  __shared__ float Ws[32][68];
  const int tid = threadIdx.x;
  const int tx = tid & 15, ty = tid >> 4;
  const int bm = blockIdx.x * 64, bn = blockIdx.y * 64;
  float acc[4][4] = {{0.f, 0.f, 0.f, 0.f}, {0.f, 0.f, 0.f, 0.f},
                     {0.f, 0.f, 0.f, 0.f}, {0.f, 0.f, 0.f, 0.f}};
  for (int kc = 0; kc < K; kc += 32) {
    for (int i = tid; i < 64 * 32; i += 256) {
      int r = i >> 5, kk = i & 31;
      int gk = kc + kk;
      int gm = bm + r, gn = bn + r;
      As[kk][r] = (gm < M && gk < K) ? A[(size_t)gm * lda + gk] : 0.f;
      Ws[kk][r] = (gn < N && gk < K) ? W[(size_t)gn * ldw + gk] : 0.f;
    }
    __syncthreads();
#pragma unroll
    for (int kk = 0; kk < 32; ++kk) {
      float4 av = *(const float4*)&As[kk][ty * 4];
      float4 bv = *(const float4*)&Ws[kk][tx * 4];
      float a4[4] = {av.x, av.y, av.z, av.w};
      float b4[4] = {bv.x, bv.y, bv.z, bv.w};
#pragma unroll
      for (int i = 0; i < 4; ++i)
#pragma unroll
        for (int j = 0; j < 4; ++j) acc[i][j] += a4[i] * b4[j];
    }
    __syncthreads();
  }
#pragma unroll
  for (int i = 0; i < 4; ++i) {
    int gm = bm + ty * 4 + i;
    if (gm >= M) continue;
#pragma unroll
    for (int j = 0; j < 4; ++j) {
      int gn = bn + tx * 4 + j;
      if (gn >= N) continue;
      float o = acc[i][j] + bias[gn];
      size_t off = (size_t)gm * ldc + gn;
      if (acc_flag) o += C[off];
      C[off] = o;
    }
  }
}

// ===================== LoRA =====================================================
__global__ __launch_bounds__(64) void lora_down(const float* __restrict__ h,
                                                const float* __restrict__ A,
                                                float* __restrict__ lt, int K) {
  const int m = blockIdx.x, lane = threadIdx.x;
  float p[8] = {0.f, 0.f, 0.f, 0.f, 0.f, 0.f, 0.f, 0.f};
  for (int kk = lane; kk < K; kk += 64) {
    float hv = h[(size_t)m * K + kk];
#pragma unroll
    for (int r = 0; r < 8; ++r) p[r] += hv * A[r * K + kk];
  }
#pragma unroll
  for (int s = 1; s < 64; s <<= 1) {
#pragma unroll
    for (int r = 0; r < 8; ++r) p[r] += __shfl_xor(p[r], s);
  }
#pragma unroll
  for (int r = 0; r < 8; ++r)
    if (lane == r) lt[m * 8 + r] = p[r];
}

__global__ __launch_bounds__(256) void lora_up(const float* __restrict__ lt,
                                               const float* __restrict__ Bm,
                                               float* __restrict__ C, int N, int total) {
  int id = blockIdx.x * 256 + threadIdx.x;
  if (id >= total) return;
  int m = id / N, n = id - m * N;
  const float* t = lt + (size_t)m * 8;
  const float* bp = Bm + (size_t)n * 8;
  float s = t[0] * bp[0] + t[1] * bp[1] + t[2] * bp[2] + t[3] * bp[3] +
            t[4] * bp[4] + t[5] * bp[5] + t[6] * bp[6] + t[7] * bp[7];
  C[id] += s;
}

// ===================== attention: one block per (head, batch) ===================
__global__ __launch_bounds__(256) void attn_kernel(const float* __restrict__ q,
                                                   const float* __restrict__ k,
                                                   const float* __restrict__ v,
                                                   float* __restrict__ ao) {
  __shared__ float qs[SEQ * 64], ks[SEQ * 64], vs[SEQ * 64], sc[SEQ * 40];
  const int head = blockIdx.x, b = blockIdx.y, tid = threadIdx.x;
  const size_t base = ((size_t)b * SEQ) * 1024 + head * 64;
  for (int i = tid; i < SEQ * 64; i += 256) {
    int s = i >> 6, d = i & 63;
    size_t off = base + (size_t)s * 1024 + d;
    qs[i] = q[off]; ks[i] = k[off]; vs[i] = v[off];
  }
  __syncthreads();
  for (int p = tid; p < SEQ * SEQ; p += 256) {
    int s = p / SEQ, t = p - s * SEQ;
    float acc = 0.f;
#pragma unroll 16
    for (int d = 0; d < 64; ++d) acc += qs[s * 64 + d] * ks[t * 64 + d];
    sc[s * 40 + t] = acc * 0.125f;  // 1/sqrt(64)
  }
  __syncthreads();
  if (tid < SEQ) {
    float m = -FLT_MAX;
    for (int t = 0; t < SEQ; ++t) m = fmaxf(m, sc[tid * 40 + t]);
    float sum = 0.f;
    for (int t = 0; t < SEQ; ++t) { float e = expf(sc[tid * 40 + t] - m); sc[tid * 40 + t] = e; sum += e; }
    float inv = 1.f / sum;
    for (int t = 0; t < SEQ; ++t) sc[tid * 40 + t] *= inv;
  }
  __syncthreads();
  for (int i = tid; i < SEQ * 64; i += 256) {
    int s = i >> 6, d = i & 63;
    float acc = 0.f;
    for (int t = 0; t < SEQ; ++t) acc += sc[s * 40 + t] * vs[t * 64 + d];
    ao[base + (size_t)s * 1024 + d] = acc;
  }
}

// ===================== gelu (exact, erf) ========================================
__global__ void gelu_kernel(float* __restrict__ x, int n) {
  int i = blockIdx.x * blockDim.x + threadIdx.x;
  if (i < n) {
    float v = x[i];
    x[i] = 0.5f * v * (1.f + erff(v * 0.70710678118654752f));
  }
}

// ===================== host =====================================================
extern "C" void kernel_launch(void* const* d_in, const int* in_sizes, int n_in,
                              void* d_out, int out_size, void* d_ws, size_t ws_size,
                              hipStream_t stream) {
  const float* hist_img = (const float*)d_in[0];
  const float* cur      = (const float*)d_in[1];
  const float* goal     = (const float*)d_in[2];
  const float* sub      = (const float*)d_in[3];
  const float* bea      = (const float*)d_in[4];
  const float* hist_pr  = (const float*)d_in[5];
  const float* prop     = (const float*)d_in[6];
  const float* bank     = (const float*)d_in[7];
  const float* hpW = (const float*)d_in[8];  const float* hpb = (const float*)d_in[9];
  const float* ipW = (const float*)d_in[10]; const float* ipb = (const float*)d_in[11];
  const float* ppW = (const float*)d_in[12]; const float* ppb = (const float*)d_in[13];
  const float* plan = (const float*)d_in[14];
  const float* ln1g = (const float*)d_in[15]; const float* ln1b = (const float*)d_in[16];
  const float* ln2g = (const float*)d_in[17]; const float* ln2b = (const float*)d_in[18];
  const float* qW = (const float*)d_in[19]; const float* qA = (const float*)d_in[20];
  const float* qB = (const float*)d_in[21]; const float* qb = (const float*)d_in[22];
  const float* kW = (const float*)d_in[23]; const float* kA = (const float*)d_in[24];
  const float* kB = (const float*)d_in[25]; const float* kb = (const float*)d_in[26];
  const float* vW = (const float*)d_in[27]; const float* vA = (const float*)d_in[28];
  const float* vB = (const float*)d_in[29]; const float* vb = (const float*)d_in[30];
  const float* oW = (const float*)d_in[31]; const float* oA = (const float*)d_in[32];
  const float* oB = (const float*)d_in[33]; const float* ob = (const float*)d_in[34];
  const float* f1W = (const float*)d_in[35]; const float* f1A = (const float*)d_in[36];
  const float* f1B = (const float*)d_in[37]; const float* f1b = (const float*)d_in[38];
  const float* f2W = (const float*)d_in[39]; const float* f2A = (const float*)d_in[40];
  const float* f2B = (const float*)d_in[41]; const float* f2b = (const float*)d_in[42];
  const float* flng = (const float*)d_in[43]; const float* flnb = (const float*)d_in[44];
  const float* ahW1 = (const float*)d_in[45]; const float* ahb1 = (const float*)d_in[46];
  const float* ahW2 = (const float*)d_in[47]; const float* ahb2 = (const float*)d_in[48];
  const float* rhW1 = (const float*)d_in[49]; const float* rhb1 = (const float*)d_in[50];
  const float* rhW2 = (const float*)d_in[51]; const float* rhb2 = (const float*)d_in[52];
  const float* shW = (const float*)d_in[53]; const float* shb = (const float*)d_in[54];
  float* out = (float*)d_out;

  // workspace layout (floats), ~52.1 MB total
  float* ws  = (float*)d_ws;
  float* F1O = ws;                              // 1184*4096 (aliases SIMS)
  float* SIMS = ws;                             // 32*100000 <= 1184*4096
  float* X   = F1O + (size_t)NTOK * 4096;
  float* Hb  = X  + (size_t)NTOK * 1024;
  float* Qb  = Hb + (size_t)NTOK * 1024;        // also tmp_hist pre-layers
  float* Kb  = Qb + (size_t)NTOK * 1024;        // also tmp_img  pre-layers
  float* Vb  = Kb + (size_t)NTOK * 1024;        // also tmp_prop pre-layers
  float* AOb = Vb + (size_t)NTOK * 1024;        // also img_in   pre-layers
  float* LT  = AOb + (size_t)NTOK * 1024;       // 1184*8
  float* SEM = LT + (size_t)NTOK * 8;           // 512*768
  float* HIN = SEM + (size_t)512 * 768;         // 512*777
  float* TKS = HIN + (size_t)512 * 777;         // 512
  int*   TKI = (int*)(TKS + 512);               // 512
  float* PS  = TKS + 1024;                      // 32*1024
  float* HH  = PS + 32 * 1024;                  // 32*1024
  float* REF = HH + 32 * 1024;                  // 32*1027

  auto gemm = [&](const float* A, int lda, const float* W, int ldw, const float* bias,
                  float* C, int ldc, int M, int N, int K, int accf) {
    dim3 g((M + 63) / 64, (N + 63) / 64);
    gemm_f32<<<g, 256, 0, stream>>>(A, lda, W, ldw, bias, C, ldc, M, N, K, accf);
  };

  // ---- retrieval ----
  sims_kernel<<<(NB + 127) / 128, 256, 0, stream>>>(cur, bank, SIMS);
  topk_kernel<<<32, 256, 0, stream>>>(SIMS, TKS, TKI);
  sem_kernel<<<512, 256, 0, stream>>>(bank, TKS, TKI, SEM);

  // ---- token embedding ----
  build_hist_in<<<512, 256, 0, stream>>>(hist_img, hist_pr, HIN);
  build_img_in<<<608, 256, 0, stream>>>(goal, sub, bea, SEM, AOb);
  gemm(HIN, 777, hpW, 777, hpb, Qb, 1024, 512, 1024, 777, 0);   // hist -> Qb
  gemm(AOb, 768, ipW, 768, ipb, Kb, 1024, 608, 1024, 768, 0);   // img  -> Kb
  gemm(prop, 9, ppW, 9, ppb, Vb, 1024, 32, 1024, 9, 0);         // prop -> Vb
  assemble_x<<<NTOK, 256, 0, stream>>>(Qb, Kb, Vb, plan, X);

  // ---- transformer layers ----
  for (int l = 0; l < 6; ++l) {
    const size_t wO = (size_t)l * 1024 * 1024, aO = (size_t)l * 8 * 1024,
                 bO = (size_t)l * 1024 * 8, biO = (size_t)l * 1024;
    ln_kernel<<<NTOK, 256, 0, stream>>>(X, 1024, Hb, ln1g + biO, ln1b + biO);
    gemm(Hb, 1024, qW + wO, 1024, qb + biO, Qb, 1024, NTOK, 1024, 1024, 0);
    lora_down<<<NTOK, 64, 0, stream>>>(Hb, qA + aO, LT, 1024);
    lora_up<<<(NTOK * 1024 + 255) / 256, 256, 0, stream>>>(LT, qB + bO, Qb, 1024, NTOK * 1024);
    gemm(Hb, 1024, kW + wO, 1024, kb + biO, Kb, 1024, NTOK, 1024, 1024, 0);
    lora_down<<<NTOK, 64, 0, stream>>>(Hb, kA + aO, LT, 1024);
    lora_up<<<(NTOK * 1024 + 255) / 256, 256, 0, stream>>>(LT, kB + bO, Kb, 1024, NTOK * 1024);
    gemm(Hb, 1024, vW + wO, 1024, vb + biO, Vb, 1024, NTOK, 1024, 1024, 0);
    lora_down<<<NTOK, 64, 0, stream>>>(Hb, vA + aO, LT, 1024);
    lora_up<<<(NTOK * 1024 + 255) / 256, 256, 0, stream>>>(LT, vB + bO, Vb, 1024, NTOK * 1024);
    attn_kernel<<<dim3(16, 32), 256, 0, stream>>>(Qb, Kb, Vb, AOb);
    gemm(AOb, 1024, oW + wO, 1024, ob + biO, X, 1024, NTOK, 1024, 1024, 1);
    lora_down<<<NTOK, 64, 0, stream>>>(AOb, oA + aO, LT, 1024);
    lora_up<<<(NTOK * 1024 + 255) / 256, 256, 0, stream>>>(LT, oB + bO, X, 1024, NTOK * 1024);
    ln_kernel<<<NTOK, 256, 0, stream>>>(X, 1024, Hb, ln2g + biO, ln2b + biO);
    const size_t w4O = (size_t)l * 4096 * 1024, a4O = (size_t)l * 8 * 4096,
                 b4O = (size_t)l * 4096 * 8, bi4O = (size_t)l * 4096;
    gemm(Hb, 1024, f1W + w4O, 1024, f1b + bi4O, F1O, 4096, NTOK, 4096, 1024, 0);
    lora_down<<<NTOK, 64, 0, stream>>>(Hb, f1A + aO, LT, 1024);
    lora_up<<<(NTOK * 4096 + 255) / 256, 256, 0, stream>>>(LT, f1B + b4O, F1O, 4096, NTOK * 4096);
    gelu_kernel<<<(NTOK * 4096 + 255) / 256, 256, 0, stream>>>(F1O, NTOK * 4096);
    gemm(F1O, 4096, f2W + w4O, 4096, f2b + biO, X, 1024, NTOK, 1024, 4096, 1);
    lora_down<<<NTOK, 64, 0, stream>>>(F1O, f2A + a4O, LT, 4096);
    lora_up<<<(NTOK * 1024 + 255) / 256, 256, 0, stream>>>(LT, f2B + bO, X, 1024, NTOK * 1024);
  }

  // ---- heads ----
  ln_kernel<<<32, 256, 0, stream>>>(X, SEQ * 1024, PS, flng, flnb);  // token 0 of each b
  gemm(PS, 1024, ahW1, 1024, ahb1, HH, 1024, 32, 1024, 1024, 0);
  gelu_kernel<<<(32 * 1024 + 255) / 256, 256, 0, stream>>>(HH, 32 * 1024);
  gemm(HH, 1024, ahW2, 1024, ahb2, out, 3, 32, 3, 1024, 0);          // anchor -> out[0:96]
  build_ref<<<32, 256, 0, stream>>>(PS, out, REF);
  gemm(REF, 1027, rhW1, 1027, rhb1, HH, 1024, 32, 1024, 1027, 0);
  gelu_kernel<<<(32 * 1024 + 255) / 256, 256, 0, stream>>>(HH, 32 * 1024);
  gemm(HH, 1024, rhW2, 1024, rhb2, out + 96, 24, 32, 24, 1024, 0);   // waypoints -> out[96:864]
  gemm(PS, 1024, shW, 1024, shb, out + 864, 1, 32, 1, 1024, 0);      // stop -> out[864:896]
}

// Round 3
// 5719.725 us; speedup vs baseline: 4.0291x; 2.2347x over previous
//
#include <hip/hip_runtime.h>
#include <float.h>
#include <math.h>

#define NB 100000
#define SEQ 37
#define NTOK 1184  // 32*37

typedef __attribute__((ext_vector_type(8))) short short8;
typedef __attribute__((ext_vector_type(4))) float floatx4;

__device__ __forceinline__ short f2bf(float f) {
  union { float f; unsigned u; } x; x.f = f;
  unsigned r = x.u + 0x7fff + ((x.u >> 16) & 1);  // round-to-nearest-even
  return (short)(r >> 16);
}

// ============ bf16 MFMA GEMM: C(M,N) = A(M,K) @ W(N,K)^T + bias ================
// Tile 128x128, BK=64, 256 thr = 4 waves, each wave a 64x64 sub-tile (4x4 frags
// of 16x16x32). fp32->bf16 RNE during reg-staging. LDS rows 128B, 16B slots
// XOR-swizzled by (row&7) on write AND read -> <=2-way conflicts (free).
__global__ __launch_bounds__(256) void gemm_bf16(const float* __restrict__ A, int lda,
                                                 const float* __restrict__ W, int ldw,
                                                 const float* __restrict__ bias,
                                                 float* __restrict__ C, int ldc,
                                                 int M, int N, int K, int acc_flag) {
  __shared__ short Al[128 * 64];
  __shared__ short Wl[128 * 64];
  const int tid = threadIdx.x;
  const int wid = tid >> 6, lane = tid & 63;
  const int wr = wid >> 1, wc = wid & 1;
  const int bm = blockIdx.x * 128, bn = blockIdx.y * 128;
  const int srow = tid >> 1;          // staging row 0..127
  const int sbase = (tid & 1) * 4;    // staging slot base {0,4}

  floatx4 acc[4][4];
#pragma unroll
  for (int i = 0; i < 4; ++i)
#pragma unroll
    for (int j = 0; j < 4; ++j)
#pragma unroll
      for (int r = 0; r < 4; ++r) acc[i][j][r] = 0.f;

  const int ga = bm + srow;           // A staging row
  const int gw = bn + srow;           // W staging row
  const bool aok = ga < M;            // N is always a multiple of 128 here
  const float* ap = A + (size_t)ga * lda;
  const float* wp = W + (size_t)gw * ldw;
  const int aswz = (srow & 7);
  const int dsbase = srow * 64;

  for (int kc = 0; kc < K; kc += 64) {
    __syncthreads();
    const bool kfull = (kc + 64 <= K);
    // ---- stage A ----
    {
      const bool fast = aok && kfull && ((lda & 3) == 0);
#pragma unroll
      for (int j = 0; j < 4; ++j) {
        const int slot = sbase + j, k0 = slot * 8;
        float v[8];
        if (fast) {
          float4 u0 = *(const float4*)(ap + kc + k0);
          float4 u1 = *(const float4*)(ap + kc + k0 + 4);
          v[0] = u0.x; v[1] = u0.y; v[2] = u0.z; v[3] = u0.w;
          v[4] = u1.x; v[5] = u1.y; v[6] = u1.z; v[7] = u1.w;
        } else {
#pragma unroll
          for (int e = 0; e < 8; ++e) {
            int kk = kc + k0 + e;
            v[e] = (aok && kk < K) ? ap[kk] : 0.f;
          }
        }
        short8 s;
#pragma unroll
        for (int e = 0; e < 8; ++e) s[e] = f2bf(v[e]);
        *(short8*)&Al[dsbase + ((slot ^ aswz) << 3)] = s;
      }
    }
    // ---- stage W ----
    {
      const bool fast = kfull && ((ldw & 3) == 0);
#pragma unroll
      for (int j = 0; j < 4; ++j) {
        const int slot = sbase + j, k0 = slot * 8;
        float v[8];
        if (fast) {
          float4 u0 = *(const float4*)(wp + kc + k0);
          float4 u1 = *(const float4*)(wp + kc + k0 + 4);
          v[0] = u0.x; v[1] = u0.y; v[2] = u0.z; v[3] = u0.w;
          v[4] = u1.x; v[5] = u1.y; v[6] = u1.z; v[7] = u1.w;
        } else {
#pragma unroll
          for (int e = 0; e < 8; ++e) {
            int kk = kc + k0 + e;
            v[e] = (kk < K) ? wp[kk] : 0.f;
          }
        }
        short8 s;
#pragma unroll
        for (int e = 0; e < 8; ++e) s[e] = f2bf(v[e]);
        *(short8*)&Wl[dsbase + ((slot ^ aswz) << 3)] = s;
      }
    }
    __syncthreads();
    // ---- compute: 2 K-steps of 32 ----
#pragma unroll
    for (int ks = 0; ks < 2; ++ks) {
      short8 af[4], wf[4];
#pragma unroll
      for (int i = 0; i < 4; ++i) {
        const int row = wr * 64 + i * 16 + (lane & 15);
        const int sa = (ks * 4 + (lane >> 4)) ^ (row & 7);
        af[i] = *(const short8*)&Al[row * 64 + sa * 8];
        const int col = wc * 64 + i * 16 + (lane & 15);
        const int sw = (ks * 4 + (lane >> 4)) ^ (col & 7);
        wf[i] = *(const short8*)&Wl[col * 64 + sw * 8];
      }
#pragma unroll
      for (int i = 0; i < 4; ++i)
#pragma unroll
        for (int j = 0; j < 4; ++j)
          acc[i][j] = __builtin_amdgcn_mfma_f32_16x16x32_bf16(af[i], wf[j], acc[i][j], 0, 0, 0);
    }
  }
  // ---- epilogue: D col=lane&15, row=(lane>>4)*4+reg ----
#pragma unroll
  for (int i = 0; i < 4; ++i) {
    const int gm0 = bm + wr * 64 + i * 16 + (lane >> 4) * 4;
#pragma unroll
    for (int j = 0; j < 4; ++j) {
      const int gn = bn + wc * 64 + j * 16 + (lane & 15);
#pragma unroll
      for (int r = 0; r < 4; ++r) {
        const int gm = gm0 + r;
        if (gm < M) {
          float o = acc[i][j][r] + bias[gn];
          size_t off = (size_t)gm * ldc + gn;
          if (acc_flag) o += C[off];
          C[off] = o;
        }
      }
    }
  }
}

// ============ sims: C(100000,32) = bank(100000,768) @ cur(32,768)^T ============
__global__ __launch_bounds__(256) void sims_kernel(const float* __restrict__ cur,
                                                   const float* __restrict__ bank,
                                                   float* __restrict__ sims) {
  __shared__ float Bs[32][132];
  __shared__ float Cs[32][36];
  const int tid = threadIdx.x;
  const int tx = tid & 7;
  const int ty = tid >> 3;
  const int n0 = blockIdx.x * 128;
  const int srow = tid >> 1;
  const int spart = tid & 1;
  const int cb = tid >> 3;
  const int ck = (tid & 7) * 4;

  float acc[4][4] = {{0.f,0.f,0.f,0.f},{0.f,0.f,0.f,0.f},
                     {0.f,0.f,0.f,0.f},{0.f,0.f,0.f,0.f}};

  const bool rok = (n0 + srow) < NB;
  const float* bp = bank + (size_t)(n0 + srow) * 768 + spart * 16;
  const float* cp = cur + (size_t)cb * 768 + ck;

  for (int kc = 0; kc < 768; kc += 32) {
    __syncthreads();
#pragma unroll
    for (int jj = 0; jj < 4; ++jj) {
      float4 v = rok ? *(const float4*)(bp + kc + jj * 4)
                     : make_float4(0.f, 0.f, 0.f, 0.f);
      const int kk = spart * 16 + jj * 4;
      Bs[kk + 0][srow] = v.x; Bs[kk + 1][srow] = v.y;
      Bs[kk + 2][srow] = v.z; Bs[kk + 3][srow] = v.w;
    }
    {
      float4 v = *(const float4*)(cp + kc);
      Cs[ck + 0][cb] = v.x; Cs[ck + 1][cb] = v.y;
      Cs[ck + 2][cb] = v.z; Cs[ck + 3][cb] = v.w;
    }
    __syncthreads();
#pragma unroll
    for (int kk = 0; kk < 32; ++kk) {
      float4 av = *(const float4*)&Bs[kk][ty * 4];
      float4 bv = *(const float4*)&Cs[kk][tx * 4];
      float a4[4] = {av.x, av.y, av.z, av.w};
      float b4[4] = {bv.x, bv.y, bv.z, bv.w};
#pragma unroll
      for (int i = 0; i < 4; ++i)
#pragma unroll
        for (int j = 0; j < 4; ++j) acc[i][j] += a4[i] * b4[j];
    }
  }
  const int n = n0 + ty * 4;
#pragma unroll
  for (int j = 0; j < 4; ++j) {
    const int b = tx * 4 + j;
    float4 o = make_float4(acc[0][j], acc[1][j], acc[2][j], acc[3][j]);
    if (n + 3 < NB) {
      *(float4*)(sims + (size_t)b * NB + n) = o;
    } else {
      float oo[4] = {o.x, o.y, o.z, o.w};
      for (int i = 0; i < 4; ++i)
        if (n + i < NB) sims[(size_t)b * NB + n + i] = oo[i];
    }
  }
}

// ===================== top-K (K=16) per batch row, ties -> lower index ==========
__global__ __launch_bounds__(256) void topk_kernel(const float* __restrict__ sims,
                                                   float* __restrict__ tks,
                                                   int* __restrict__ tki) {
  __shared__ float ss[4096];
  __shared__ int si[4096];
  __shared__ float wv[4];
  __shared__ int wi[4];
  const int b = blockIdx.x, tid = threadIdx.x;
  float ls[16]; int li[16];
#pragma unroll
  for (int i = 0; i < 16; ++i) { ls[i] = -FLT_MAX; li[i] = 0x7fffffff; }
  const float* row = sims + (size_t)b * NB;
  float lmin = -FLT_MAX;
  for (int n = tid; n < NB; n += 256) {
    float v = row[n];
    if (v > lmin) {
      int p = 15;
      while (p > 0 && ls[p - 1] < v) { ls[p] = ls[p - 1]; li[p] = li[p - 1]; --p; }
      ls[p] = v; li[p] = n;
      lmin = ls[15];
    }
  }
#pragma unroll
  for (int i = 0; i < 16; ++i) { ss[i * 256 + tid] = ls[i]; si[i * 256 + tid] = li[i]; }
  __syncthreads();
  for (int round = 0; round < 16; ++round) {
    float bv = -FLT_MAX; int bi = 0x7fffffff;
#pragma unroll
    for (int i = 0; i < 16; ++i) {
      float v = ss[i * 256 + tid]; int ix = si[i * 256 + tid];
      if (v > bv || (v == bv && ix < bi)) { bv = v; bi = ix; }
    }
#pragma unroll
    for (int s = 32; s; s >>= 1) {
      float ov = __shfl_down(bv, s); int oi = __shfl_down(bi, s);
      if (ov > bv || (ov == bv && oi < bi)) { bv = ov; bi = oi; }
    }
    if ((tid & 63) == 0) { wv[tid >> 6] = bv; wi[tid >> 6] = bi; }
    __syncthreads();
    if (tid == 0) {
      bv = wv[0]; bi = wi[0];
      for (int w = 1; w < 4; ++w)
        if (wv[w] > bv || (wv[w] == bv && wi[w] < bi)) { bv = wv[w]; bi = wi[w]; }
      tks[b * 16 + round] = bv; tki[b * 16 + round] = bi;
      wi[0] = bi;
    }
    __syncthreads();
    bi = wi[0];
#pragma unroll
    for (int i = 0; i < 16; ++i)
      if (si[i * 256 + tid] == bi) ss[i * 256 + tid] = -FLT_MAX;
    __syncthreads();
  }
}

// ===================== small copy/assembly kernels ==============================
__global__ void sem_kernel(const float* __restrict__ bank, const float* __restrict__ tks,
                           const int* __restrict__ tki, float* __restrict__ sem) {
  int slot = blockIdx.x;
  float s = tks[slot]; int idx = tki[slot];
  for (int i = threadIdx.x; i < 768; i += 256)
    sem[(size_t)slot * 768 + i] = bank[(size_t)idx * 768 + i] * s;
}

__global__ void build_hist_in(const float* __restrict__ img, const float* __restrict__ pr,
                              float* __restrict__ out) {
  int r = blockIdx.x;
  for (int i = threadIdx.x; i < 777; i += 256)
    out[(size_t)r * 777 + i] = (i < 768) ? img[(size_t)r * 768 + i] : pr[r * 9 + (i - 768)];
}

__global__ void build_img_in(const float* __restrict__ goal, const float* __restrict__ sub,
                             const float* __restrict__ bea, const float* __restrict__ sem,
                             float* __restrict__ out) {
  int r = blockIdx.x;
  const float* src = (r < 32) ? goal + (size_t)r * 768
                   : (r < 64) ? sub + (size_t)(r - 32) * 768
                   : (r < 96) ? bea + (size_t)(r - 64) * 768
                              : sem + (size_t)(r - 96) * 768;
  for (int i = threadIdx.x; i < 768; i += 256) out[(size_t)r * 768 + i] = src[i];
}

__global__ void assemble_x(const float* __restrict__ th, const float* __restrict__ ti,
                           const float* __restrict__ tp, const float* __restrict__ plan,
                           float* __restrict__ x) {
  int r = blockIdx.x;
  int b = r / SEQ, tok = r - b * SEQ;
  const float* src;
  if (tok == 0) src = plan;
  else if (tok <= 16) src = th + (size_t)(b * 16 + tok - 1) * 1024;
  else if (tok <= 19) src = ti + (size_t)((tok - 17) * 32 + b) * 1024;
  else if (tok <= 35) src = ti + (size_t)(96 + b * 16 + (tok - 20)) * 1024;
  else src = tp + (size_t)b * 1024;
  for (int i = threadIdx.x; i < 1024; i += 256) x[(size_t)r * 1024 + i] = src[i];
}

__global__ void build_ref(const float* __restrict__ ps, const float* __restrict__ anc,
                          float* __restrict__ ref) {
  int b = blockIdx.x;
  for (int i = threadIdx.x; i < 1027; i += 256)
    ref[(size_t)b * 1027 + i] = (i < 1024) ? ps[(size_t)b * 1024 + i] : anc[b * 3 + (i - 1024)];
}

// ===================== layernorm ===============================================
__device__ __forceinline__ float block_sum256(float v, float* red) {
#pragma unroll
  for (int s = 32; s; s >>= 1) v += __shfl_down(v, s);
  if ((threadIdx.x & 63) == 0) red[threadIdx.x >> 6] = v;
  __syncthreads();
  float tot = red[0] + red[1] + red[2] + red[3];
  __syncthreads();
  return tot;
}

__global__ __launch_bounds__(256) void ln_kernel(const float* __restrict__ in, int in_stride,
                                                 float* __restrict__ out,
                                                 const float* __restrict__ g,
                                                 const float* __restrict__ bt) {
  __shared__ float red[4];
  const float* xr = in + (size_t)blockIdx.x * in_stride;
  const int tid = threadIdx.x;
  float v[4];
#pragma unroll
  for (int i = 0; i < 4; ++i) v[i] = xr[tid + 256 * i];
  float mean = block_sum256(v[0] + v[1] + v[2] + v[3], red) * (1.f / 1024.f);
  float sq = 0.f;
#pragma unroll
  for (int i = 0; i < 4; ++i) { float d = v[i] - mean; sq += d * d; }
  float var = block_sum256(sq, red) * (1.f / 1024.f);
  float inv = rsqrtf(var + 1e-5f);
  float* orow = out + (size_t)blockIdx.x * 1024;
#pragma unroll
  for (int i = 0; i < 4; ++i) {
    int c = tid + 256 * i;
    orow[c] = (v[i] - mean) * inv * g[c] + bt[c];
  }
}

// ===================== generic fp32 GEMM (small shapes only) ====================
__global__ __launch_bounds__(256) void gemm_f32(const float* __restrict__ A, int lda,
                                                const float* __restrict__ W, int ldw,
                                                const float* __restrict__ bias,
                                                float* __restrict__ C, int ldc,
                                                int M, int N, int K, int acc_flag) {
  __shared__ float As[32][68];
  __shared__ float Ws[32][68];
  const int tid = threadIdx.x;
  const int tx = tid & 15, ty = tid >> 4;
  const int bm = blockIdx.x * 64, bn = blockIdx.y * 64;
  float acc[4][4] = {{0.f, 0.f, 0.f, 0.f}, {0.f, 0.f, 0.f, 0.f},
                     {0.f, 0.f, 0.f, 0.f}, {0.f, 0.f, 0.f, 0.f}};
  for (int kc = 0; kc < K; kc += 32) {
    for (int i = tid; i < 64 * 32; i += 256) {
      int r = i >> 5, kk = i & 31;
      int gk = kc + kk;
      int gm = bm + r, gn = bn + r;
      As[kk][r] = (gm < M && gk < K) ? A[(size_t)gm * lda + gk] : 0.f;
      Ws[kk][r] = (gn < N && gk < K) ? W[(size_t)gn * ldw + gk] : 0.f;
    }
    __syncthreads();
#pragma unroll
    for (int kk = 0; kk < 32; ++kk) {
      float4 av = *(const float4*)&As[kk][ty * 4];
      float4 bv = *(const float4*)&Ws[kk][tx * 4];
      float a4[4] = {av.x, av.y, av.z, av.w};
      float b4[4] = {bv.x, bv.y, bv.z, bv.w};
#pragma unroll
      for (int i = 0; i < 4; ++i)
#pragma unroll
        for (int j = 0; j < 4; ++j) acc[i][j] += a4[i] * b4[j];
    }
    __syncthreads();
  }
#pragma unroll
  for (int i = 0; i < 4; ++i) {
    int gm = bm + ty * 4 + i;
    if (gm >= M) continue;
#pragma unroll
    for (int j = 0; j < 4; ++j) {
      int gn = bn + tx * 4 + j;
      if (gn >= N) continue;
      float o = acc[i][j] + bias[gn];
      size_t off = (size_t)gm * ldc + gn;
      if (acc_flag) o += C[off];
      C[off] = o;
    }
  }
}

// ===================== LoRA =====================================================
__global__ __launch_bounds__(64) void lora_down(const float* __restrict__ h,
                                                const float* __restrict__ A,
                                                float* __restrict__ lt, int K) {
  const int m = blockIdx.x, lane = threadIdx.x;
  float p[8] = {0.f, 0.f, 0.f, 0.f, 0.f, 0.f, 0.f, 0.f};
  for (int kk = lane; kk < K; kk += 64) {
    float hv = h[(size_t)m * K + kk];
#pragma unroll
    for (int r = 0; r < 8; ++r) p[r] += hv * A[r * K + kk];
  }
#pragma unroll
  for (int s = 1; s < 64; s <<= 1) {
#pragma unroll
    for (int r = 0; r < 8; ++r) p[r] += __shfl_xor(p[r], s);
  }
#pragma unroll
  for (int r = 0; r < 8; ++r)
    if (lane == r) lt[m * 8 + r] = p[r];
}

__global__ __launch_bounds__(256) void lora_up(const float* __restrict__ lt,
                                               const float* __restrict__ Bm,
                                               float* __restrict__ C, int N, int total) {
  int id = blockIdx.x * 256 + threadIdx.x;
  if (id >= total) return;
  int m = id / N, n = id - m * N;
  const float* t = lt + (size_t)m * 8;
  const float* bp = Bm + (size_t)n * 8;
  float s = t[0] * bp[0] + t[1] * bp[1] + t[2] * bp[2] + t[3] * bp[3] +
            t[4] * bp[4] + t[5] * bp[5] + t[6] * bp[6] + t[7] * bp[7];
  C[id] += s;
}

// ===================== attention ================================================
__global__ __launch_bounds__(256) void attn_kernel(const float* __restrict__ q,
                                                   const float* __restrict__ k,
                                                   const float* __restrict__ v,
                                                   float* __restrict__ ao) {
  __shared__ float qs[SEQ * 64], ks[SEQ * 64], vs[SEQ * 64], sc[SEQ * 40];
  const int head = blockIdx.x, b = blockIdx.y, tid = threadIdx.x;
  const size_t base = ((size_t)b * SEQ) * 1024 + head * 64;
  for (int i = tid; i < SEQ * 64; i += 256) {
    int s = i >> 6, d = i & 63;
    size_t off = base + (size_t)s * 1024 + d;
    qs[i] = q[off]; ks[i] = k[off]; vs[i] = v[off];
  }
  __syncthreads();
  for (int p = tid; p < SEQ * SEQ; p += 256) {
    int s = p / SEQ, t = p - s * SEQ;
    float acc = 0.f;
#pragma unroll 16
    for (int d = 0; d < 64; ++d) acc += qs[s * 64 + d] * ks[t * 64 + d];
    sc[s * 40 + t] = acc * 0.125f;
  }
  __syncthreads();
  if (tid < SEQ) {
    float m = -FLT_MAX;
    for (int t = 0; t < SEQ; ++t) m = fmaxf(m, sc[tid * 40 + t]);
    float sum = 0.f;
    for (int t = 0; t < SEQ; ++t) { float e = expf(sc[tid * 40 + t] - m); sc[tid * 40 + t] = e; sum += e; }
    float inv = 1.f / sum;
    for (int t = 0; t < SEQ; ++t) sc[tid * 40 + t] *= inv;
  }
  __syncthreads();
  for (int i = tid; i < SEQ * 64; i += 256) {
    int s = i >> 6, d = i & 63;
    float acc = 0.f;
    for (int t = 0; t < SEQ; ++t) acc += sc[s * 40 + t] * vs[t * 64 + d];
    ao[base + (size_t)s * 1024 + d] = acc;
  }
}

// ===================== gelu (exact, erf) ========================================
__global__ void gelu_kernel(float* __restrict__ x, int n) {
  int i = blockIdx.x * blockDim.x + threadIdx.x;
  if (i < n) {
    float v = x[i];
    x[i] = 0.5f * v * (1.f + erff(v * 0.70710678118654752f));
  }
}

// ===================== host =====================================================
extern "C" void kernel_launch(void* const* d_in, const int* in_sizes, int n_in,
                              void* d_out, int out_size, void* d_ws, size_t ws_size,
                              hipStream_t stream) {
  const float* hist_img = (const float*)d_in[0];
  const float* cur      = (const float*)d_in[1];
  const float* goal     = (const float*)d_in[2];
  const float* sub      = (const float*)d_in[3];
  const float* bea      = (const float*)d_in[4];
  const float* hist_pr  = (const float*)d_in[5];
  const float* prop     = (const float*)d_in[6];
  const float* bank     = (const float*)d_in[7];
  const float* hpW = (const float*)d_in[8];  const float* hpb = (const float*)d_in[9];
  const float* ipW = (const float*)d_in[10]; const float* ipb = (const float*)d_in[11];
  const float* ppW = (const float*)d_in[12]; const float* ppb = (const float*)d_in[13];
  const float* plan = (const float*)d_in[14];
  const float* ln1g = (const float*)d_in[15]; const float* ln1b = (const float*)d_in[16];
  const float* ln2g = (const float*)d_in[17]; const float* ln2b = (const float*)d_in[18];
  const float* qW = (const float*)d_in[19]; const float* qA = (const float*)d_in[20];
  const float* qB = (const float*)d_in[21]; const float* qb = (const float*)d_in[22];
  const float* kW = (const float*)d_in[23]; const float* kA = (const float*)d_in[24];
  const float* kB = (const float*)d_in[25]; const float* kb = (const float*)d_in[26];
  const float* vW = (const float*)d_in[27]; const float* vA = (const float*)d_in[28];
  const float* vB = (const float*)d_in[29]; const float* vb = (const float*)d_in[30];
  const float* oW = (const float*)d_in[31]; const float* oA = (const float*)d_in[32];
  const float* oB = (const float*)d_in[33]; const float* ob = (const float*)d_in[34];
  const float* f1W = (const float*)d_in[35]; const float* f1A = (const float*)d_in[36];
  const float* f1B = (const float*)d_in[37]; const float* f1b = (const float*)d_in[38];
  const float* f2W = (const float*)d_in[39]; const float* f2A = (const float*)d_in[40];
  const float* f2B = (const float*)d_in[41]; const float* f2b = (const float*)d_in[42];
  const float* flng = (const float*)d_in[43]; const float* flnb = (const float*)d_in[44];
  const float* ahW1 = (const float*)d_in[45]; const float* ahb1 = (const float*)d_in[46];
  const float* ahW2 = (const float*)d_in[47]; const float* ahb2 = (const float*)d_in[48];
  const float* rhW1 = (const float*)d_in[49]; const float* rhb1 = (const float*)d_in[50];
  const float* rhW2 = (const float*)d_in[51]; const float* rhb2 = (const float*)d_in[52];
  const float* shW = (const float*)d_in[53]; const float* shb = (const float*)d_in[54];
  float* out = (float*)d_out;

  float* ws  = (float*)d_ws;
  float* F1O = ws;
  float* SIMS = ws;
  float* X   = F1O + (size_t)NTOK * 4096;
  float* Hb  = X  + (size_t)NTOK * 1024;
  float* Qb  = Hb + (size_t)NTOK * 1024;
  float* Kb  = Qb + (size_t)NTOK * 1024;
  float* Vb  = Kb + (size_t)NTOK * 1024;
  float* AOb = Vb + (size_t)NTOK * 1024;
  float* LT  = AOb + (size_t)NTOK * 1024;
  float* SEM = LT + (size_t)NTOK * 8;
  float* HIN = SEM + (size_t)512 * 768;
  float* TKS = HIN + (size_t)512 * 777;
  int*   TKI = (int*)(TKS + 512);
  float* PS  = TKS + 1024;
  float* HH  = PS + 32 * 1024;
  float* REF = HH + 32 * 1024;

  auto gemmb = [&](const float* A, int lda, const float* W, int ldw, const float* bias,
                   float* C, int ldc, int M, int N, int K, int accf) {
    dim3 g((M + 127) / 128, N / 128);  // N is always a multiple of 128 here
    gemm_bf16<<<g, 256, 0, stream>>>(A, lda, W, ldw, bias, C, ldc, M, N, K, accf);
  };
  auto gemm = [&](const float* A, int lda, const float* W, int ldw, const float* bias,
                  float* C, int ldc, int M, int N, int K, int accf) {
    dim3 g((M + 63) / 64, (N + 63) / 64);
    gemm_f32<<<g, 256, 0, stream>>>(A, lda, W, ldw, bias, C, ldc, M, N, K, accf);
  };

  // ---- retrieval ----
  sims_kernel<<<(NB + 127) / 128, 256, 0, stream>>>(cur, bank, SIMS);
  topk_kernel<<<32, 256, 0, stream>>>(SIMS, TKS, TKI);
  sem_kernel<<<512, 256, 0, stream>>>(bank, TKS, TKI, SEM);

  // ---- token embedding ----
  build_hist_in<<<512, 256, 0, stream>>>(hist_img, hist_pr, HIN);
  build_img_in<<<608, 256, 0, stream>>>(goal, sub, bea, SEM, AOb);
  gemmb(HIN, 777, hpW, 777, hpb, Qb, 1024, 512, 1024, 777, 0);
  gemmb(AOb, 768, ipW, 768, ipb, Kb, 1024, 608, 1024, 768, 0);
  gemm(prop, 9, ppW, 9, ppb, Vb, 1024, 32, 1024, 9, 0);
  assemble_x<<<NTOK, 256, 0, stream>>>(Qb, Kb, Vb, plan, X);

  // ---- transformer layers ----
  for (int l = 0; l < 6; ++l) {
    const size_t wO = (size_t)l * 1024 * 1024, aO = (size_t)l * 8 * 1024,
                 bO = (size_t)l * 1024 * 8, biO = (size_t)l * 1024;
    ln_kernel<<<NTOK, 256, 0, stream>>>(X, 1024, Hb, ln1g + biO, ln1b + biO);
    gemmb(Hb, 1024, qW + wO, 1024, qb + biO, Qb, 1024, NTOK, 1024, 1024, 0);
    lora_down<<<NTOK, 64, 0, stream>>>(Hb, qA + aO, LT, 1024);
    lora_up<<<(NTOK * 1024 + 255) / 256, 256, 0, stream>>>(LT, qB + bO, Qb, 1024, NTOK * 1024);
    gemmb(Hb, 1024, kW + wO, 1024, kb + biO, Kb, 1024, NTOK, 1024, 1024, 0);
    lora_down<<<NTOK, 64, 0, stream>>>(Hb, kA + aO, LT, 1024);
    lora_up<<<(NTOK * 1024 + 255) / 256, 256, 0, stream>>>(LT, kB + bO, Kb, 1024, NTOK * 1024);
    gemmb(Hb, 1024, vW + wO, 1024, vb + biO, Vb, 1024, NTOK, 1024, 1024, 0);
    lora_down<<<NTOK, 64, 0, stream>>>(Hb, vA + aO, LT, 1024);
    lora_up<<<(NTOK * 1024 + 255) / 256, 256, 0, stream>>>(LT, vB + bO, Vb, 1024, NTOK * 1024);
    attn_kernel<<<dim3(16, 32), 256, 0, stream>>>(Qb, Kb, Vb, AOb);
    gemmb(AOb, 1024, oW + wO, 1024, ob + biO, X, 1024, NTOK, 1024, 1024, 1);
    lora_down<<<NTOK, 64, 0, stream>>>(AOb, oA + aO, LT, 1024);
    lora_up<<<(NTOK * 1024 + 255) / 256, 256, 0, stream>>>(LT, oB + bO, X, 1024, NTOK * 1024);
    ln_kernel<<<NTOK, 256, 0, stream>>>(X, 1024, Hb, ln2g + biO, ln2b + biO);
    const size_t w4O = (size_t)l * 4096 * 1024, a4O = (size_t)l * 8 * 4096,
                 b4O = (size_t)l * 4096 * 8, bi4O = (size_t)l * 4096;
    gemmb(Hb, 1024, f1W + w4O, 1024, f1b + bi4O, F1O, 4096, NTOK, 4096, 1024, 0);
    lora_down<<<NTOK, 64, 0, stream>>>(Hb, f1A + aO, LT, 1024);
    lora_up<<<(NTOK * 4096 + 255) / 256, 256, 0, stream>>>(LT, f1B + b4O, F1O, 4096, NTOK * 4096);
    gelu_kernel<<<(NTOK * 4096 + 255) / 256, 256, 0, stream>>>(F1O, NTOK * 4096);
    gemmb(F1O, 4096, f2W + w4O, 4096, f2b + biO, X, 1024, NTOK, 1024, 4096, 1);
    lora_down<<<NTOK, 64, 0, stream>>>(F1O, f2A + a4O, LT, 4096);
    lora_up<<<(NTOK * 1024 + 255) / 256, 256, 0, stream>>>(LT, f2B + bO, X, 1024, NTOK * 1024);
  }

  // ---- heads ----
  ln_kernel<<<32, 256, 0, stream>>>(X, SEQ * 1024, PS, flng, flnb);
  gemm(PS, 1024, ahW1, 1024, ahb1, HH, 1024, 32, 1024, 1024, 0);
  gelu_kernel<<<(32 * 1024 + 255) / 256, 256, 0, stream>>>(HH, 32 * 1024);
  gemm(HH, 1024, ahW2, 1024, ahb2, out, 3, 32, 3, 1024, 0);
  build_ref<<<32, 256, 0, stream>>>(PS, out, REF);
  gemm(REF, 1027, rhW1, 1027, rhb1, HH, 1024, 32, 1024, 1027, 0);
  gelu_kernel<<<(32 * 1024 + 255) / 256, 256, 0, stream>>>(HH, 32 * 1024);
  gemm(HH, 1024, rhW2, 1024, rhb2, out + 96, 24, 32, 24, 1024, 0);
  gemm(PS, 1024, shW, 1024, shb, out + 864, 1, 32, 1, 1024, 0);
}

// Round 4
// 4520.452 us; speedup vs baseline: 5.0981x; 1.2653x over previous
//
#include <hip/hip_runtime.h>
#include <float.h>
#include <math.h>

#define NB 100000
#define SEQ 37
#define NTOK 1184  // 32*37
#define TKCH 16    // top-k stage-1 chunks (16*6250 = 100000)

typedef __attribute__((ext_vector_type(8))) short short8;
typedef __attribute__((ext_vector_type(4))) float floatx4;

__device__ __forceinline__ short f2bf(float f) {
  union { float f; unsigned u; } x; x.f = f;
  unsigned r = x.u + 0x7fff + ((x.u >> 16) & 1);  // round-to-nearest-even
  return (short)(r >> 16);
}

__device__ __forceinline__ float gelu_f(float v) {
  return 0.5f * v * (1.f + erff(v * 0.70710678118654752f));
}

// ============ bf16 MFMA GEMM: C(M,N) = A(M,K) @ W(N,K)^T + bias ================
// Tile 128x128, BK=64, 4 waves, each wave 64x64 (4x4 frags of 16x16x32).
// fp32->bf16 RNE during reg-staging. 16B LDS slots XOR-swizzled by (row&7).
// blockIdx.z selects among up to 3 fused GEMMs sharing A (e.g. Q/K/V).
__global__ __launch_bounds__(256) void gemm_bf16(const float* __restrict__ A, int lda,
                                                 const float* __restrict__ W0,
                                                 const float* __restrict__ W1,
                                                 const float* __restrict__ W2, int ldw,
                                                 const float* __restrict__ b0,
                                                 const float* __restrict__ b1,
                                                 const float* __restrict__ b2,
                                                 float* __restrict__ C, size_t czstride,
                                                 int ldc, int M, int N, int K, int acc_flag) {
  __shared__ short Al[128 * 64];
  __shared__ short Wl[128 * 64];
  const int z = blockIdx.z;
  const float* W = (z == 0) ? W0 : (z == 1) ? W1 : W2;
  const float* bias = (z == 0) ? b0 : (z == 1) ? b1 : b2;
  C += (size_t)z * czstride;
  const int tid = threadIdx.x;
  const int wid = tid >> 6, lane = tid & 63;
  const int wr = wid >> 1, wc = wid & 1;
  const int bm = blockIdx.x * 128, bn = blockIdx.y * 128;
  const int srow = tid >> 1;
  const int sbase = (tid & 1) * 4;

  floatx4 acc[4][4];
#pragma unroll
  for (int i = 0; i < 4; ++i)
#pragma unroll
    for (int j = 0; j < 4; ++j)
#pragma unroll
      for (int r = 0; r < 4; ++r) acc[i][j][r] = 0.f;

  const int ga = bm + srow;
  const int gw = bn + srow;
  const bool aok = ga < M;
  const float* ap = A + (size_t)ga * lda;
  const float* wp = W + (size_t)gw * ldw;
  const int aswz = (srow & 7);
  const int dsbase = srow * 64;

  for (int kc = 0; kc < K; kc += 64) {
    __syncthreads();
    const bool kfull = (kc + 64 <= K);
    {
      const bool fast = aok && kfull && ((lda & 3) == 0);
#pragma unroll
      for (int j = 0; j < 4; ++j) {
        const int slot = sbase + j, k0 = slot * 8;
        float v[8];
        if (fast) {
          float4 u0 = *(const float4*)(ap + kc + k0);
          float4 u1 = *(const float4*)(ap + kc + k0 + 4);
          v[0] = u0.x; v[1] = u0.y; v[2] = u0.z; v[3] = u0.w;
          v[4] = u1.x; v[5] = u1.y; v[6] = u1.z; v[7] = u1.w;
        } else {
#pragma unroll
          for (int e = 0; e < 8; ++e) {
            int kk = kc + k0 + e;
            v[e] = (aok && kk < K) ? ap[kk] : 0.f;
          }
        }
        short8 s;
#pragma unroll
        for (int e = 0; e < 8; ++e) s[e] = f2bf(v[e]);
        *(short8*)&Al[dsbase + ((slot ^ aswz) << 3)] = s;
      }
    }
    {
      const bool fast = kfull && ((ldw & 3) == 0);
#pragma unroll
      for (int j = 0; j < 4; ++j) {
        const int slot = sbase + j, k0 = slot * 8;
        float v[8];
        if (fast) {
          float4 u0 = *(const float4*)(wp + kc + k0);
          float4 u1 = *(const float4*)(wp + kc + k0 + 4);
          v[0] = u0.x; v[1] = u0.y; v[2] = u0.z; v[3] = u0.w;
          v[4] = u1.x; v[5] = u1.y; v[6] = u1.z; v[7] = u1.w;
        } else {
#pragma unroll
          for (int e = 0; e < 8; ++e) {
            int kk = kc + k0 + e;
            v[e] = (kk < K) ? wp[kk] : 0.f;
          }
        }
        short8 s;
#pragma unroll
        for (int e = 0; e < 8; ++e) s[e] = f2bf(v[e]);
        *(short8*)&Wl[dsbase + ((slot ^ aswz) << 3)] = s;
      }
    }
    __syncthreads();
#pragma unroll
    for (int ks = 0; ks < 2; ++ks) {
      short8 af[4], wf[4];
#pragma unroll
      for (int i = 0; i < 4; ++i) {
        const int row = wr * 64 + i * 16 + (lane & 15);
        const int sa = (ks * 4 + (lane >> 4)) ^ (row & 7);
        af[i] = *(const short8*)&Al[row * 64 + sa * 8];
        const int col = wc * 64 + i * 16 + (lane & 15);
        const int sw = (ks * 4 + (lane >> 4)) ^ (col & 7);
        wf[i] = *(const short8*)&Wl[col * 64 + sw * 8];
      }
#pragma unroll
      for (int i = 0; i < 4; ++i)
#pragma unroll
        for (int j = 0; j < 4; ++j)
          acc[i][j] = __builtin_amdgcn_mfma_f32_16x16x32_bf16(af[i], wf[j], acc[i][j], 0, 0, 0);
    }
  }
#pragma unroll
  for (int i = 0; i < 4; ++i) {
    const int gm0 = bm + wr * 64 + i * 16 + (lane >> 4) * 4;
#pragma unroll
    for (int j = 0; j < 4; ++j) {
      const int gn = bn + wc * 64 + j * 16 + (lane & 15);
#pragma unroll
      for (int r = 0; r < 4; ++r) {
        const int gm = gm0 + r;
        if (gm < M) {
          float o = acc[i][j][r] + bias[gn];
          size_t off = (size_t)gm * ldc + gn;
          if (acc_flag) o += C[off];
          C[off] = o;
        }
      }
    }
  }
}

// ============ sims: C(100000,32) = bank(100000,768) @ cur(32,768)^T ============
__global__ __launch_bounds__(256) void sims_kernel(const float* __restrict__ cur,
                                                   const float* __restrict__ bank,
                                                   float* __restrict__ sims) {
  __shared__ float Bs[32][132];
  __shared__ float Cs[32][36];
  const int tid = threadIdx.x;
  const int tx = tid & 7;
  const int ty = tid >> 3;
  const int n0 = blockIdx.x * 128;
  const int srow = tid >> 1;
  const int spart = tid & 1;
  const int cb = tid >> 3;
  const int ck = (tid & 7) * 4;

  float acc[4][4] = {{0.f,0.f,0.f,0.f},{0.f,0.f,0.f,0.f},
                     {0.f,0.f,0.f,0.f},{0.f,0.f,0.f,0.f}};

  const bool rok = (n0 + srow) < NB;
  const float* bp = bank + (size_t)(n0 + srow) * 768 + spart * 16;
  const float* cp = cur + (size_t)cb * 768 + ck;

  for (int kc = 0; kc < 768; kc += 32) {
    __syncthreads();
#pragma unroll
    for (int jj = 0; jj < 4; ++jj) {
      float4 v = rok ? *(const float4*)(bp + kc + jj * 4)
                     : make_float4(0.f, 0.f, 0.f, 0.f);
      const int kk = spart * 16 + jj * 4;
      Bs[kk + 0][srow] = v.x; Bs[kk + 1][srow] = v.y;
      Bs[kk + 2][srow] = v.z; Bs[kk + 3][srow] = v.w;
    }
    {
      float4 v = *(const float4*)(cp + kc);
      Cs[ck + 0][cb] = v.x; Cs[ck + 1][cb] = v.y;
      Cs[ck + 2][cb] = v.z; Cs[ck + 3][cb] = v.w;
    }
    __syncthreads();
#pragma unroll
    for (int kk = 0; kk < 32; ++kk) {
      float4 av = *(const float4*)&Bs[kk][ty * 4];
      float4 bv = *(const float4*)&Cs[kk][tx * 4];
      float a4[4] = {av.x, av.y, av.z, av.w};
      float b4[4] = {bv.x, bv.y, bv.z, bv.w};
#pragma unroll
      for (int i = 0; i < 4; ++i)
#pragma unroll
        for (int j = 0; j < 4; ++j) acc[i][j] += a4[i] * b4[j];
    }
  }
  const int n = n0 + ty * 4;
#pragma unroll
  for (int j = 0; j < 4; ++j) {
    const int b = tx * 4 + j;
    float4 o = make_float4(acc[0][j], acc[1][j], acc[2][j], acc[3][j]);
    if (n + 3 < NB) {
      *(float4*)(sims + (size_t)b * NB + n) = o;
    } else {
      float oo[4] = {o.x, o.y, o.z, o.w};
      for (int i = 0; i < 4; ++i)
        if (n + i < NB) sims[(size_t)b * NB + n + i] = oo[i];
    }
  }
}

// ===================== top-K stage 1: per-(row,chunk) top-16 ====================
// grid (TKCH, 32). Each block scans 6250 elements, emits 16 candidates.
__global__ __launch_bounds__(256) void topk_stage1(const float* __restrict__ sims,
                                                   float* __restrict__ cv,
                                                   int* __restrict__ ci) {
  __shared__ float ss[4096];
  __shared__ int si[4096];
  __shared__ float wv[4];
  __shared__ int wi[4];
  const int chunk = blockIdx.x, b = blockIdx.y, tid = threadIdx.x;
  const int start = chunk * (NB / TKCH), end = start + (NB / TKCH);
  float ls[16]; int li[16];
#pragma unroll
  for (int i = 0; i < 16; ++i) { ls[i] = -FLT_MAX; li[i] = 0x7fffffff; }
  const float* row = sims + (size_t)b * NB;
  float lmin = -FLT_MAX;
  for (int n = start + tid; n < end; n += 256) {
    float v = row[n];
    if (v > lmin) {  // strict > keeps earlier (lower) index on ties
      int p = 15;
      while (p > 0 && ls[p - 1] < v) { ls[p] = ls[p - 1]; li[p] = li[p - 1]; --p; }
      ls[p] = v; li[p] = n;
      lmin = ls[15];
    }
  }
#pragma unroll
  for (int i = 0; i < 16; ++i) { ss[i * 256 + tid] = ls[i]; si[i * 256 + tid] = li[i]; }
  __syncthreads();
  for (int round = 0; round < 16; ++round) {
    float bv = -FLT_MAX; int bi = 0x7fffffff;
#pragma unroll
    for (int i = 0; i < 16; ++i) {
      float v = ss[i * 256 + tid]; int ix = si[i * 256 + tid];
      if (v > bv || (v == bv && ix < bi)) { bv = v; bi = ix; }
    }
#pragma unroll
    for (int s = 32; s; s >>= 1) {
      float ov = __shfl_down(bv, s); int oi = __shfl_down(bi, s);
      if (ov > bv || (ov == bv && oi < bi)) { bv = ov; bi = oi; }
    }
    if ((tid & 63) == 0) { wv[tid >> 6] = bv; wi[tid >> 6] = bi; }
    __syncthreads();
    if (tid == 0) {
      bv = wv[0]; bi = wi[0];
      for (int w = 1; w < 4; ++w)
        if (wv[w] > bv || (wv[w] == bv && wi[w] < bi)) { bv = wv[w]; bi = wi[w]; }
      cv[(b * TKCH + chunk) * 16 + round] = bv;
      ci[(b * TKCH + chunk) * 16 + round] = bi;
      wi[0] = bi;
    }
    __syncthreads();
    bi = wi[0];
#pragma unroll
    for (int i = 0; i < 16; ++i)
      if (si[i * 256 + tid] == bi) ss[i * 256 + tid] = -FLT_MAX;
    __syncthreads();
  }
}

// ===================== top-K stage 2: 256 candidates -> top-16 ==================
__global__ __launch_bounds__(256) void topk_stage2(const float* __restrict__ cv,
                                                   const int* __restrict__ ci,
                                                   float* __restrict__ tks,
                                                   int* __restrict__ tki) {
  __shared__ float wv[4];
  __shared__ int wi[4];
  __shared__ int bw;
  const int b = blockIdx.x, tid = threadIdx.x;
  float val = cv[b * 256 + tid];
  int idx = ci[b * 256 + tid];
  for (int round = 0; round < 16; ++round) {
    float bv = val; int bi = idx;
#pragma unroll
    for (int s = 1; s < 64; s <<= 1) {
      float ov = __shfl_xor(bv, s); int oi = __shfl_xor(bi, s);
      if (ov > bv || (ov == bv && oi < bi)) { bv = ov; bi = oi; }
    }
    if ((tid & 63) == 0) { wv[tid >> 6] = bv; wi[tid >> 6] = bi; }
    __syncthreads();
    if (tid == 0) {
      bv = wv[0]; bi = wi[0];
      for (int w = 1; w < 4; ++w)
        if (wv[w] > bv || (wv[w] == bv && wi[w] < bi)) { bv = wv[w]; bi = wi[w]; }
      tks[b * 16 + round] = bv; tki[b * 16 + round] = bi;
      bw = bi;
    }
    __syncthreads();
    if (idx == bw) val = -FLT_MAX;
  }
}

// ===================== small copy/assembly kernels ==============================
__global__ void sem_kernel(const float* __restrict__ bank, const float* __restrict__ tks,
                           const int* __restrict__ tki, float* __restrict__ sem) {
  int slot = blockIdx.x;
  float s = tks[slot]; int idx = tki[slot];
  for (int i = threadIdx.x; i < 768; i += 256)
    sem[(size_t)slot * 768 + i] = bank[(size_t)idx * 768 + i] * s;
}

__global__ void build_hist_in(const float* __restrict__ img, const float* __restrict__ pr,
                              float* __restrict__ out) {
  int r = blockIdx.x;
  for (int i = threadIdx.x; i < 777; i += 256)
    out[(size_t)r * 777 + i] = (i < 768) ? img[(size_t)r * 768 + i] : pr[r * 9 + (i - 768)];
}

__global__ void build_img_in(const float* __restrict__ goal, const float* __restrict__ sub,
                             const float* __restrict__ bea, const float* __restrict__ sem,
                             float* __restrict__ out) {
  int r = blockIdx.x;
  const float* src = (r < 32) ? goal + (size_t)r * 768
                   : (r < 64) ? sub + (size_t)(r - 32) * 768
                   : (r < 96) ? bea + (size_t)(r - 64) * 768
                              : sem + (size_t)(r - 96) * 768;
  for (int i = threadIdx.x; i < 768; i += 256) out[(size_t)r * 768 + i] = src[i];
}

__global__ void assemble_x(const float* __restrict__ th, const float* __restrict__ ti,
                           const float* __restrict__ tp, const float* __restrict__ plan,
                           float* __restrict__ x) {
  int r = blockIdx.x;
  int b = r / SEQ, tok = r - b * SEQ;
  const float* src;
  if (tok == 0) src = plan;
  else if (tok <= 16) src = th + (size_t)(b * 16 + tok - 1) * 1024;
  else if (tok <= 19) src = ti + (size_t)((tok - 17) * 32 + b) * 1024;
  else if (tok <= 35) src = ti + (size_t)(96 + b * 16 + (tok - 20)) * 1024;
  else src = tp + (size_t)b * 1024;
  for (int i = threadIdx.x; i < 1024; i += 256) x[(size_t)r * 1024 + i] = src[i];
}

__global__ void build_ref(const float* __restrict__ ps, const float* __restrict__ anc,
                          float* __restrict__ ref) {
  int b = blockIdx.x;
  for (int i = threadIdx.x; i < 1027; i += 256)
    ref[(size_t)b * 1027 + i] = (i < 1024) ? ps[(size_t)b * 1024 + i] : anc[b * 3 + (i - 1024)];
}

// ===================== layernorm ===============================================
__device__ __forceinline__ float block_sum256(float v, float* red) {
#pragma unroll
  for (int s = 32; s; s >>= 1) v += __shfl_down(v, s);
  if ((threadIdx.x & 63) == 0) red[threadIdx.x >> 6] = v;
  __syncthreads();
  float tot = red[0] + red[1] + red[2] + red[3];
  __syncthreads();
  return tot;
}

__global__ __launch_bounds__(256) void ln_kernel(const float* __restrict__ in, int in_stride,
                                                 float* __restrict__ out,
                                                 const float* __restrict__ g,
                                                 const float* __restrict__ bt) {
  __shared__ float red[4];
  const float* xr = in + (size_t)blockIdx.x * in_stride;
  const int tid = threadIdx.x;
  float v[4];
#pragma unroll
  for (int i = 0; i < 4; ++i) v[i] = xr[tid + 256 * i];
  float mean = block_sum256(v[0] + v[1] + v[2] + v[3], red) * (1.f / 1024.f);
  float sq = 0.f;
#pragma unroll
  for (int i = 0; i < 4; ++i) { float d = v[i] - mean; sq += d * d; }
  float var = block_sum256(sq, red) * (1.f / 1024.f);
  float inv = rsqrtf(var + 1e-5f);
  float* orow = out + (size_t)blockIdx.x * 1024;
#pragma unroll
  for (int i = 0; i < 4; ++i) {
    int c = tid + 256 * i;
    orow[c] = (v[i] - mean) * inv * g[c] + bt[c];
  }
}

// ===================== generic fp32 GEMM (small shapes only) ====================
__global__ __launch_bounds__(256) void gemm_f32(const float* __restrict__ A, int lda,
                                                const float* __restrict__ W, int ldw,
                                                const float* __restrict__ bias,
                                                float* __restrict__ C, int ldc,
                                                int M, int N, int K, int acc_flag) {
  __shared__ float As[32][68];
  __shared__ float Ws[32][68];
  const int tid = threadIdx.x;
  const int tx = tid & 15, ty = tid >> 4;
  const int bm = blockIdx.x * 64, bn = blockIdx.y * 64;
  float acc[4][4] = {{0.f, 0.f, 0.f, 0.f}, {0.f, 0.f, 0.f, 0.f},
                     {0.f, 0.f, 0.f, 0.f}, {0.f, 0.f, 0.f, 0.f}};
  for (int kc = 0; kc < K; kc += 32) {
    for (int i = tid; i < 64 * 32; i += 256) {
      int r = i >> 5, kk = i & 31;
      int gk = kc + kk;
      int gm = bm + r, gn = bn + r;
      As[kk][r] = (gm < M && gk < K) ? A[(size_t)gm * lda + gk] : 0.f;
      Ws[kk][r] = (gn < N && gk < K) ? W[(size_t)gn * ldw + gk] : 0.f;
    }
    __syncthreads();
#pragma unroll
    for (int kk = 0; kk < 32; ++kk) {
      float4 av = *(const float4*)&As[kk][ty * 4];
      float4 bv = *(const float4*)&Ws[kk][tx * 4];
      float a4[4] = {av.x, av.y, av.z, av.w};
      float b4[4] = {bv.x, bv.y, bv.z, bv.w};
#pragma unroll
      for (int i = 0; i < 4; ++i)
#pragma unroll
        for (int j = 0; j < 4; ++j) acc[i][j] += a4[i] * b4[j];
    }
    __syncthreads();
  }
#pragma unroll
  for (int i = 0; i < 4; ++i) {
    int gm = bm + ty * 4 + i;
    if (gm >= M) continue;
#pragma unroll
    for (int j = 0; j < 4; ++j) {
      int gn = bn + tx * 4 + j;
      if (gn >= N) continue;
      float o = acc[i][j] + bias[gn];
      size_t off = (size_t)gm * ldc + gn;
      if (acc_flag) o += C[off];
      C[off] = o;
    }
  }
}

// ===================== LoRA (multi: blockIdx.y selects among up to 3) ===========
__global__ __launch_bounds__(64) void lora_down(const float* __restrict__ h,
                                                const float* __restrict__ A0,
                                                const float* __restrict__ A1,
                                                const float* __restrict__ A2,
                                                float* __restrict__ lt, int K) {
  const int m = blockIdx.x, z = blockIdx.y, lane = threadIdx.x;
  const float* A = (z == 0) ? A0 : (z == 1) ? A1 : A2;
  float p[8] = {0.f, 0.f, 0.f, 0.f, 0.f, 0.f, 0.f, 0.f};
  for (int kk = lane; kk < K; kk += 64) {
    float hv = h[(size_t)m * K + kk];
#pragma unroll
    for (int r = 0; r < 8; ++r) p[r] += hv * A[r * K + kk];
  }
#pragma unroll
  for (int s = 1; s < 64; s <<= 1) {
#pragma unroll
    for (int r = 0; r < 8; ++r) p[r] += __shfl_xor(p[r], s);
  }
#pragma unroll
  for (int r = 0; r < 8; ++r)
    if (lane == r) lt[((size_t)z * NTOK + m) * 8 + r] = p[r];
}

__global__ __launch_bounds__(256) void lora_up(const float* __restrict__ lt,
                                               const float* __restrict__ B0,
                                               const float* __restrict__ B1,
                                               const float* __restrict__ B2,
                                               float* __restrict__ C, size_t czstride,
                                               int N, int total, int gelu_flag) {
  int id = blockIdx.x * 256 + threadIdx.x;
  if (id >= total) return;
  const int z = blockIdx.y;
  const float* Bm = (z == 0) ? B0 : (z == 1) ? B1 : B2;
  C += (size_t)z * czstride;
  int m = id / N, n = id - m * N;
  const float* t = lt + ((size_t)z * NTOK + m) * 8;
  const float* bp = Bm + (size_t)n * 8;
  float s = t[0] * bp[0] + t[1] * bp[1] + t[2] * bp[2] + t[3] * bp[3] +
            t[4] * bp[4] + t[5] * bp[5] + t[6] * bp[6] + t[7] * bp[7];
  float o = C[id] + s;
  C[id] = gelu_flag ? gelu_f(o) : o;
}

// ===================== attention ================================================
__global__ __launch_bounds__(256) void attn_kernel(const float* __restrict__ q,
                                                   const float* __restrict__ k,
                                                   const float* __restrict__ v,
                                                   float* __restrict__ ao) {
  __shared__ float qs[SEQ * 64], ks[SEQ * 64], vs[SEQ * 64], sc[SEQ * 40];
  const int head = blockIdx.x, b = blockIdx.y, tid = threadIdx.x;
  const size_t base = ((size_t)b * SEQ) * 1024 + head * 64;
  for (int i = tid; i < SEQ * 64; i += 256) {
    int s = i >> 6, d = i & 63;
    size_t off = base + (size_t)s * 1024 + d;
    qs[i] = q[off]; ks[i] = k[off]; vs[i] = v[off];
  }
  __syncthreads();
  for (int p = tid; p < SEQ * SEQ; p += 256) {
    int s = p / SEQ, t = p - s * SEQ;
    float acc = 0.f;
#pragma unroll 16
    for (int d = 0; d < 64; ++d) acc += qs[s * 64 + d] * ks[t * 64 + d];
    sc[s * 40 + t] = acc * 0.125f;
  }
  __syncthreads();
  if (tid < SEQ) {
    float m = -FLT_MAX;
    for (int t = 0; t < SEQ; ++t) m = fmaxf(m, sc[tid * 40 + t]);
    float sum = 0.f;
    for (int t = 0; t < SEQ; ++t) { float e = expf(sc[tid * 40 + t] - m); sc[tid * 40 + t] = e; sum += e; }
    float inv = 1.f / sum;
    for (int t = 0; t < SEQ; ++t) sc[tid * 40 + t] *= inv;
  }
  __syncthreads();
  for (int i = tid; i < SEQ * 64; i += 256) {
    int s = i >> 6, d = i & 63;
    float acc = 0.f;
    for (int t = 0; t < SEQ; ++t) acc += sc[s * 40 + t] * vs[t * 64 + d];
    ao[base + (size_t)s * 1024 + d] = acc;
  }
}

// ===================== gelu (exact, erf) ========================================
__global__ void gelu_kernel(float* __restrict__ x, int n) {
  int i = blockIdx.x * blockDim.x + threadIdx.x;
  if (i < n) x[i] = gelu_f(x[i]);
}

// ===================== host =====================================================
extern "C" void kernel_launch(void* const* d_in, const int* in_sizes, int n_in,
                              void* d_out, int out_size, void* d_ws, size_t ws_size,
                              hipStream_t stream) {
  const float* hist_img = (const float*)d_in[0];
  const float* cur      = (const float*)d_in[1];
  const float* goal     = (const float*)d_in[2];
  const float* sub      = (const float*)d_in[3];
  const float* bea      = (const float*)d_in[4];
  const float* hist_pr  = (const float*)d_in[5];
  const float* prop     = (const float*)d_in[6];
  const float* bank     = (const float*)d_in[7];
  const float* hpW = (const float*)d_in[8];  const float* hpb = (const float*)d_in[9];
  const float* ipW = (const float*)d_in[10]; const float* ipb = (const float*)d_in[11];
  const float* ppW = (const float*)d_in[12]; const float* ppb = (const float*)d_in[13];
  const float* plan = (const float*)d_in[14];
  const float* ln1g = (const float*)d_in[15]; const float* ln1b = (const float*)d_in[16];
  const float* ln2g = (const float*)d_in[17]; const float* ln2b = (const float*)d_in[18];
  const float* qW = (const float*)d_in[19]; const float* qA = (const float*)d_in[20];
  const float* qB = (const float*)d_in[21]; const float* qb = (const float*)d_in[22];
  const float* kW = (const float*)d_in[23]; const float* kA = (const float*)d_in[24];
  const float* kB = (const float*)d_in[25]; const float* kb = (const float*)d_in[26];
  const float* vW = (const float*)d_in[27]; const float* vA = (const float*)d_in[28];
  const float* vB = (const float*)d_in[29]; const float* vb = (const float*)d_in[30];
  const float* oW = (const float*)d_in[31]; const float* oA = (const float*)d_in[32];
  const float* oB = (const float*)d_in[33]; const float* ob = (const float*)d_in[34];
  const float* f1W = (const float*)d_in[35]; const float* f1A = (const float*)d_in[36];
  const float* f1B = (const float*)d_in[37]; const float* f1b = (const float*)d_in[38];
  const float* f2W = (const float*)d_in[39]; const float* f2A = (const float*)d_in[40];
  const float* f2B = (const float*)d_in[41]; const float* f2b = (const float*)d_in[42];
  const float* flng = (const float*)d_in[43]; const float* flnb = (const float*)d_in[44];
  const float* ahW1 = (const float*)d_in[45]; const float* ahb1 = (const float*)d_in[46];
  const float* ahW2 = (const float*)d_in[47]; const float* ahb2 = (const float*)d_in[48];
  const float* rhW1 = (const float*)d_in[49]; const float* rhb1 = (const float*)d_in[50];
  const float* rhW2 = (const float*)d_in[51]; const float* rhb2 = (const float*)d_in[52];
  const float* shW = (const float*)d_in[53]; const float* shb = (const float*)d_in[54];
  float* out = (float*)d_out;

  float* ws  = (float*)d_ws;
  float* F1O = ws;
  float* SIMS = ws;
  float* X   = F1O + (size_t)NTOK * 4096;
  float* Hb  = X  + (size_t)NTOK * 1024;
  float* Qb  = Hb + (size_t)NTOK * 1024;
  float* Kb  = Qb + (size_t)NTOK * 1024;
  float* Vb  = Kb + (size_t)NTOK * 1024;
  float* AOb = Vb + (size_t)NTOK * 1024;
  float* LT  = AOb + (size_t)NTOK * 1024;      // 3*NTOK*8
  float* SEM = LT + (size_t)3 * NTOK * 8;      // 512*768
  float* HIN = SEM + (size_t)512 * 768;        // 512*777
  float* TKS = HIN + (size_t)512 * 777;        // 512
  int*   TKI = (int*)(TKS + 512);              // 512
  float* PS  = TKS + 1024;                     // 32*1024
  float* HH  = PS + 32 * 1024;                 // 32*1024
  float* REF = HH + 32 * 1024;                 // 32*1027
  float* CV  = REF + 32 * 1027;                // 32*256
  int*   CI  = (int*)(CV + 32 * 256);          // 32*256

  const size_t czs = (size_t)NTOK * 1024;

  auto gemmb1 = [&](const float* A, int lda, const float* W, int ldw, const float* bias,
                    float* C, int ldc, int M, int N, int K, int accf) {
    dim3 g((M + 127) / 128, N / 128, 1);
    gemm_bf16<<<g, 256, 0, stream>>>(A, lda, W, W, W, ldw, bias, bias, bias,
                                     C, 0, ldc, M, N, K, accf);
  };
  auto gemm = [&](const float* A, int lda, const float* W, int ldw, const float* bias,
                  float* C, int ldc, int M, int N, int K, int accf) {
    dim3 g((M + 63) / 64, (N + 63) / 64);
    gemm_f32<<<g, 256, 0, stream>>>(A, lda, W, ldw, bias, C, ldc, M, N, K, accf);
  };

  // ---- retrieval ----
  sims_kernel<<<(NB + 127) / 128, 256, 0, stream>>>(cur, bank, SIMS);
  topk_stage1<<<dim3(TKCH, 32), 256, 0, stream>>>(SIMS, CV, CI);
  topk_stage2<<<32, 256, 0, stream>>>(CV, CI, TKS, TKI);
  sem_kernel<<<512, 256, 0, stream>>>(bank, TKS, TKI, SEM);

  // ---- token embedding ----
  build_hist_in<<<512, 256, 0, stream>>>(hist_img, hist_pr, HIN);
  build_img_in<<<608, 256, 0, stream>>>(goal, sub, bea, SEM, AOb);
  gemmb1(HIN, 777, hpW, 777, hpb, Qb, 1024, 512, 1024, 777, 0);
  gemmb1(AOb, 768, ipW, 768, ipb, Kb, 1024, 608, 1024, 768, 0);
  gemm(prop, 9, ppW, 9, ppb, Vb, 1024, 32, 1024, 9, 0);
  assemble_x<<<NTOK, 256, 0, stream>>>(Qb, Kb, Vb, plan, X);

  // ---- transformer layers ----
  const int upb = (NTOK * 1024 + 255) / 256;
  for (int l = 0; l < 6; ++l) {
    const size_t wO = (size_t)l * 1024 * 1024, aO = (size_t)l * 8 * 1024,
                 bO = (size_t)l * 1024 * 8, biO = (size_t)l * 1024;
    ln_kernel<<<NTOK, 256, 0, stream>>>(X, 1024, Hb, ln1g + biO, ln1b + biO);
    // fused QKV
    gemm_bf16<<<dim3((NTOK + 127) / 128, 8, 3), 256, 0, stream>>>(
        Hb, 1024, qW + wO, kW + wO, vW + wO, 1024, qb + biO, kb + biO, vb + biO,
        Qb, czs, 1024, NTOK, 1024, 1024, 0);
    lora_down<<<dim3(NTOK, 3), 64, 0, stream>>>(Hb, qA + aO, kA + aO, vA + aO, LT, 1024);
    lora_up<<<dim3(upb, 3), 256, 0, stream>>>(LT, qB + bO, kB + bO, vB + bO,
                                              Qb, czs, 1024, NTOK * 1024, 0);
    attn_kernel<<<dim3(16, 32), 256, 0, stream>>>(Qb, Kb, Vb, AOb);
    gemmb1(AOb, 1024, oW + wO, 1024, ob + biO, X, 1024, NTOK, 1024, 1024, 1);
    lora_down<<<dim3(NTOK, 1), 64, 0, stream>>>(AOb, oA + aO, oA + aO, oA + aO, LT, 1024);
    lora_up<<<dim3(upb, 1), 256, 0, stream>>>(LT, oB + bO, oB + bO, oB + bO,
                                              X, 0, 1024, NTOK * 1024, 0);
    ln_kernel<<<NTOK, 256, 0, stream>>>(X, 1024, Hb, ln2g + biO, ln2b + biO);
    const size_t w4O = (size_t)l * 4096 * 1024, a4O = (size_t)l * 8 * 4096,
                 b4O = (size_t)l * 4096 * 8, bi4O = (size_t)l * 4096;
    gemmb1(Hb, 1024, f1W + w4O, 1024, f1b + bi4O, F1O, 4096, NTOK, 4096, 1024, 0);
    lora_down<<<dim3(NTOK, 1), 64, 0, stream>>>(Hb, f1A + aO, f1A + aO, f1A + aO, LT, 1024);
    lora_up<<<dim3((NTOK * 4096 + 255) / 256, 1), 256, 0, stream>>>(
        LT, f1B + b4O, f1B + b4O, f1B + b4O, F1O, 0, 4096, NTOK * 4096, 1);  // +gelu
    gemmb1(F1O, 4096, f2W + w4O, 4096, f2b + biO, X, 1024, NTOK, 1024, 4096, 1);
    lora_down<<<dim3(NTOK, 1), 64, 0, stream>>>(F1O, f2A + a4O, f2A + a4O, f2A + a4O, LT, 4096);
    lora_up<<<dim3(upb, 1), 256, 0, stream>>>(LT, f2B + bO, f2B + bO, f2B + bO,
                                              X, 0, 1024, NTOK * 1024, 0);
  }

  // ---- heads ----
  ln_kernel<<<32, 256, 0, stream>>>(X, SEQ * 1024, PS, flng, flnb);
  gemm(PS, 1024, ahW1, 1024, ahb1, HH, 1024, 32, 1024, 1024, 0);
  gelu_kernel<<<(32 * 1024 + 255) / 256, 256, 0, stream>>>(HH, 32 * 1024);
  gemm(HH, 1024, ahW2, 1024, ahb2, out, 3, 32, 3, 1024, 0);
  build_ref<<<32, 256, 0, stream>>>(PS, out, REF);
  gemm(REF, 1027, rhW1, 1027, rhb1, HH, 1024, 32, 1024, 1027, 0);
  gelu_kernel<<<(32 * 1024 + 255) / 256, 256, 0, stream>>>(HH, 32 * 1024);
  gemm(HH, 1024, rhW2, 1024, rhb2, out + 96, 24, 32, 24, 1024, 0);
  gemm(PS, 1024, shW, 1024, shb, out + 864, 1, 32, 1, 1024, 0);
}

// Round 5
// 3801.870 us; speedup vs baseline: 6.0616x; 1.1890x over previous
//
#include <hip/hip_runtime.h>
#include <float.h>
#include <math.h>

#define NB 100000
#define SEQ 37
#define NTOK 1184  // 32*37
#define TKCH 16    // top-k stage-1 chunks (16*6250 = 100000)

typedef __attribute__((ext_vector_type(8))) short short8;
typedef __attribute__((ext_vector_type(4))) float floatx4;

__device__ __forceinline__ short f2bf(float f) {
  union { float f; unsigned u; } x; x.f = f;
  unsigned r = x.u + 0x7fff + ((x.u >> 16) & 1);  // round-to-nearest-even
  return (short)(r >> 16);
}

__device__ __forceinline__ float gelu_f(float v) {
  return 0.5f * v * (1.f + erff(v * 0.70710678118654752f));
}

// ===================== per-layer weight conversion ==============================
// Converts q,k,v,o (1024x1024), f1 (4096x1024), f2 (1024x4096) fp32 weights to
// bf16 in the GEMM's tiled+swizzled LDS layout:
//   tile(np,kc) base = weight_off + (np*nkc + kc)*8192
//   element (row,col) at  row*64 + ((col>>3) ^ (row&7))*8 + (col&7)
// so the GEMM stages W with pure linear 16B copies.
__global__ __launch_bounds__(256) void wconv(const float* __restrict__ q,
                                             const float* __restrict__ k,
                                             const float* __restrict__ v,
                                             const float* __restrict__ o,
                                             const float* __restrict__ f1,
                                             const float* __restrict__ f2,
                                             short* __restrict__ wb) {
  const int t = blockIdx.x;  // 0..1535
  const float* src; int Kd; size_t doff; int np, kc;
  if (t < 512) {           // q,k,v,o: 128 tiles each (np 0..7, kc 0..15)
    const int w = t >> 7, ti = t & 127;
    src = (w == 0) ? q : (w == 1) ? k : (w == 2) ? v : o;
    Kd = 1024; np = ti >> 4; kc = ti & 15;
    doff = (size_t)w * 1048576 + ((size_t)np * 16 + kc) * 8192;
  } else if (t < 1024) {   // f1: np 0..31, kc 0..15
    const int ti = t - 512;
    src = f1; Kd = 1024; np = ti >> 4; kc = ti & 15;
    doff = (size_t)4 * 1048576 + ((size_t)np * 16 + kc) * 8192;
  } else {                 // f2: np 0..7, kc 0..63
    const int ti = t - 1024;
    src = f2; Kd = 4096; np = ti >> 6; kc = ti & 63;
    doff = (size_t)8 * 1048576 + ((size_t)np * 64 + kc) * 8192;
  }
  const int tid = threadIdx.x;
  const int row = tid >> 1;
  const float* sp = src + (size_t)(np * 128 + row) * Kd + kc * 64;
  short* dp = wb + doff + row * 64;
  const int sw = row & 7;
#pragma unroll
  for (int j = 0; j < 4; ++j) {
    const int slot = (tid & 1) * 4 + j;
    float4 u0 = *(const float4*)(sp + slot * 8);
    float4 u1 = *(const float4*)(sp + slot * 8 + 4);
    short8 s;
    s[0] = f2bf(u0.x); s[1] = f2bf(u0.y); s[2] = f2bf(u0.z); s[3] = f2bf(u0.w);
    s[4] = f2bf(u1.x); s[5] = f2bf(u1.y); s[6] = f2bf(u1.z); s[7] = f2bf(u1.w);
    *(short8*)(dp + ((slot ^ sw) << 3)) = s;
  }
}

// ============ MFMA GEMM, bf16-tiled weights: C = A(M,K)@W^T + bias =============
// A fp32 row-major (lda mult of 4); W pre-converted by wconv. Tile 128x128,
// BK=64, 4 waves, reg-double-buffered K-loop (load t+1 | compute t | write t+1),
// one barrier per K-step. blockIdx.z picks fused weight/bias/output (QKV).
__global__ __launch_bounds__(256) void gemm_bt(const float* __restrict__ A, int lda,
                                               const short* __restrict__ WT, size_t wzstride,
                                               const float* __restrict__ b0,
                                               const float* __restrict__ b1,
                                               const float* __restrict__ b2,
                                               float* __restrict__ C, size_t czstride,
                                               int ldc, int M, int K, int acc_flag) {
  __shared__ short Al[2][128 * 64];
  __shared__ short Wl[2][128 * 64];
  const int z = blockIdx.z;
  const float* bias = (z == 0) ? b0 : (z == 1) ? b1 : b2;
  C += (size_t)z * czstride;
  const int nkc = K >> 6;
  const short* wt = WT + (size_t)z * wzstride + (size_t)blockIdx.y * nkc * 8192;
  const int tid = threadIdx.x;
  const int wid = tid >> 6, lane = tid & 63;
  const int wr = wid >> 1, wc = wid & 1;
  const int bm = blockIdx.x * 128, bn = blockIdx.y * 128;
  const int srow = tid >> 1;
  const int sbase = (tid & 1) * 4;

  floatx4 acc[4][4];
#pragma unroll
  for (int i = 0; i < 4; ++i)
#pragma unroll
    for (int j = 0; j < 4; ++j)
#pragma unroll
      for (int r = 0; r < 4; ++r) acc[i][j][r] = 0.f;

  const int ga = bm + srow;
  const bool aok = ga < M;
  const float* ap = A + (size_t)ga * lda;
  const int aswz = srow & 7;

  float4 ar[8];    // A prefetch: 32 floats
  short8 wreg[4];  // W prefetch: 32 shorts

#define LOAD_A(kc_)                                                        \
  {                                                                        \
    _Pragma("unroll") for (int j = 0; j < 4; ++j) {                        \
      const int slot = sbase + j;                                          \
      if (aok) {                                                           \
        ar[j * 2] = *(const float4*)(ap + (kc_)*64 + slot * 8);            \
        ar[j * 2 + 1] = *(const float4*)(ap + (kc_)*64 + slot * 8 + 4);    \
      } else {                                                             \
        ar[j * 2] = make_float4(0.f, 0.f, 0.f, 0.f);                      \
        ar[j * 2 + 1] = make_float4(0.f, 0.f, 0.f, 0.f);                  \
      }                                                                    \
    }                                                                      \
  }
#define LOAD_W(kc_)                                                        \
  {                                                                        \
    _Pragma("unroll") for (int it = 0; it < 4; ++it)                       \
        wreg[it] = *(const short8*)(wt + (size_t)(kc_)*8192 + (it * 256 + tid) * 8); \
  }
#define WRITE_A(buf_)                                                      \
  {                                                                        \
    _Pragma("unroll") for (int j = 0; j < 4; ++j) {                        \
      const int slot = sbase + j;                                          \
      short8 s;                                                            \
      s[0] = f2bf(ar[j * 2].x); s[1] = f2bf(ar[j * 2].y);                  \
      s[2] = f2bf(ar[j * 2].z); s[3] = f2bf(ar[j * 2].w);                  \
      s[4] = f2bf(ar[j * 2 + 1].x); s[5] = f2bf(ar[j * 2 + 1].y);          \
      s[6] = f2bf(ar[j * 2 + 1].z); s[7] = f2bf(ar[j * 2 + 1].w);          \
      *(short8*)&Al[buf_][srow * 64 + ((slot ^ aswz) << 3)] = s;           \
    }                                                                      \
  }
#define WRITE_W(buf_)                                                      \
  {                                                                        \
    _Pragma("unroll") for (int it = 0; it < 4; ++it)                       \
        *(short8*)&Wl[buf_][(it * 256 + tid) * 8] = wreg[it];              \
  }

  LOAD_W(0) LOAD_A(0)
  WRITE_A(0) WRITE_W(0)
  __syncthreads();

  for (int t = 0; t < nkc; ++t) {
    const int cur = t & 1, nxt = cur ^ 1;
    const bool more = (t + 1 < nkc);
    if (more) { LOAD_W(t + 1) LOAD_A(t + 1) }
#pragma unroll
    for (int ks = 0; ks < 2; ++ks) {
      short8 af[4], wf[4];
#pragma unroll
      for (int i = 0; i < 4; ++i) {
        const int row = wr * 64 + i * 16 + (lane & 15);
        const int sa = (ks * 4 + (lane >> 4)) ^ (row & 7);
        af[i] = *(const short8*)&Al[cur][row * 64 + sa * 8];
        const int col = wc * 64 + i * 16 + (lane & 15);
        const int sw2 = (ks * 4 + (lane >> 4)) ^ (col & 7);
        wf[i] = *(const short8*)&Wl[cur][col * 64 + sw2 * 8];
      }
#pragma unroll
      for (int i = 0; i < 4; ++i)
#pragma unroll
        for (int j = 0; j < 4; ++j)
          acc[i][j] = __builtin_amdgcn_mfma_f32_16x16x32_bf16(af[i], wf[j], acc[i][j], 0, 0, 0);
    }
    if (more) { WRITE_A(nxt) WRITE_W(nxt) }
    __syncthreads();
  }
#undef LOAD_A
#undef LOAD_W
#undef WRITE_A
#undef WRITE_W

#pragma unroll
  for (int i = 0; i < 4; ++i) {
    const int gm0 = bm + wr * 64 + i * 16 + (lane >> 4) * 4;
#pragma unroll
    for (int j = 0; j < 4; ++j) {
      const int gn = bn + wc * 64 + j * 16 + (lane & 15);
#pragma unroll
      for (int r = 0; r < 4; ++r) {
        const int gm = gm0 + r;
        if (gm < M) {
          float o = acc[i][j][r] + bias[gn];
          size_t off = (size_t)gm * ldc + gn;
          if (acc_flag) o += C[off];
          C[off] = o;
        }
      }
    }
  }
}

// ============ legacy bf16 GEMM (fp32 weights) for embed GEMMs ==================
__global__ __launch_bounds__(256) void gemm_bf16(const float* __restrict__ A, int lda,
                                                 const float* __restrict__ W, int ldw,
                                                 const float* __restrict__ bias,
                                                 float* __restrict__ C,
                                                 int ldc, int M, int N, int K, int acc_flag) {
  __shared__ short Al[128 * 64];
  __shared__ short Wl[128 * 64];
  const int tid = threadIdx.x;
  const int wid = tid >> 6, lane = tid & 63;
  const int wr = wid >> 1, wc = wid & 1;
  const int bm = blockIdx.x * 128, bn = blockIdx.y * 128;
  const int srow = tid >> 1;
  const int sbase = (tid & 1) * 4;

  floatx4 acc[4][4];
#pragma unroll
  for (int i = 0; i < 4; ++i)
#pragma unroll
    for (int j = 0; j < 4; ++j)
#pragma unroll
      for (int r = 0; r < 4; ++r) acc[i][j][r] = 0.f;

  const int ga = bm + srow;
  const int gw = bn + srow;
  const bool aok = ga < M;
  const float* ap = A + (size_t)ga * lda;
  const float* wp = W + (size_t)gw * ldw;
  const int aswz = (srow & 7);
  const int dsbase = srow * 64;

  for (int kc = 0; kc < K; kc += 64) {
    __syncthreads();
    const bool kfull = (kc + 64 <= K);
    {
      const bool fast = aok && kfull && ((lda & 3) == 0);
#pragma unroll
      for (int j = 0; j < 4; ++j) {
        const int slot = sbase + j, k0 = slot * 8;
        float v[8];
        if (fast) {
          float4 u0 = *(const float4*)(ap + kc + k0);
          float4 u1 = *(const float4*)(ap + kc + k0 + 4);
          v[0] = u0.x; v[1] = u0.y; v[2] = u0.z; v[3] = u0.w;
          v[4] = u1.x; v[5] = u1.y; v[6] = u1.z; v[7] = u1.w;
        } else {
#pragma unroll
          for (int e = 0; e < 8; ++e) {
            int kk = kc + k0 + e;
            v[e] = (aok && kk < K) ? ap[kk] : 0.f;
          }
        }
        short8 s;
#pragma unroll
        for (int e = 0; e < 8; ++e) s[e] = f2bf(v[e]);
        *(short8*)&Al[dsbase + ((slot ^ aswz) << 3)] = s;
      }
    }
    {
      const bool fast = kfull && ((ldw & 3) == 0);
#pragma unroll
      for (int j = 0; j < 4; ++j) {
        const int slot = sbase + j, k0 = slot * 8;
        float v[8];
        if (fast) {
          float4 u0 = *(const float4*)(wp + kc + k0);
          float4 u1 = *(const float4*)(wp + kc + k0 + 4);
          v[0] = u0.x; v[1] = u0.y; v[2] = u0.z; v[3] = u0.w;
          v[4] = u1.x; v[5] = u1.y; v[6] = u1.z; v[7] = u1.w;
        } else {
#pragma unroll
          for (int e = 0; e < 8; ++e) {
            int kk = kc + k0 + e;
            v[e] = (kk < K) ? wp[kk] : 0.f;
          }
        }
        short8 s;
#pragma unroll
        for (int e = 0; e < 8; ++e) s[e] = f2bf(v[e]);
        *(short8*)&Wl[dsbase + ((slot ^ aswz) << 3)] = s;
      }
    }
    __syncthreads();
#pragma unroll
    for (int ks = 0; ks < 2; ++ks) {
      short8 af[4], wf[4];
#pragma unroll
      for (int i = 0; i < 4; ++i) {
        const int row = wr * 64 + i * 16 + (lane & 15);
        const int sa = (ks * 4 + (lane >> 4)) ^ (row & 7);
        af[i] = *(const short8*)&Al[row * 64 + sa * 8];
        const int col = wc * 64 + i * 16 + (lane & 15);
        const int sw = (ks * 4 + (lane >> 4)) ^ (col & 7);
        wf[i] = *(const short8*)&Wl[col * 64 + sw * 8];
      }
#pragma unroll
      for (int i = 0; i < 4; ++i)
#pragma unroll
        for (int j = 0; j < 4; ++j)
          acc[i][j] = __builtin_amdgcn_mfma_f32_16x16x32_bf16(af[i], wf[j], acc[i][j], 0, 0, 0);
    }
  }
#pragma unroll
  for (int i = 0; i < 4; ++i) {
    const int gm0 = bm + wr * 64 + i * 16 + (lane >> 4) * 4;
#pragma unroll
    for (int j = 0; j < 4; ++j) {
      const int gn = bn + wc * 64 + j * 16 + (lane & 15);
#pragma unroll
      for (int r = 0; r < 4; ++r) {
        const int gm = gm0 + r;
        if (gm < M) {
          float o = acc[i][j][r] + bias[gn];
          size_t off = (size_t)gm * ldc + gn;
          if (acc_flag) o += C[off];
          C[off] = o;
        }
      }
    }
  }
}

// ============ sims: C(100000,32) = bank(100000,768) @ cur(32,768)^T ============
__global__ __launch_bounds__(256) void sims_kernel(const float* __restrict__ cur,
                                                   const float* __restrict__ bank,
                                                   float* __restrict__ sims) {
  __shared__ float Bs[32][132];
  __shared__ float Cs[32][36];
  const int tid = threadIdx.x;
  const int tx = tid & 7;
  const int ty = tid >> 3;
  const int n0 = blockIdx.x * 128;
  const int srow = tid >> 1;
  const int spart = tid & 1;
  const int cb = tid >> 3;
  const int ck = (tid & 7) * 4;

  float acc[4][4] = {{0.f,0.f,0.f,0.f},{0.f,0.f,0.f,0.f},
                     {0.f,0.f,0.f,0.f},{0.f,0.f,0.f,0.f}};

  const bool rok = (n0 + srow) < NB;
  const float* bp = bank + (size_t)(n0 + srow) * 768 + spart * 16;
  const float* cp = cur + (size_t)cb * 768 + ck;

  for (int kc = 0; kc < 768; kc += 32) {
    __syncthreads();
#pragma unroll
    for (int jj = 0; jj < 4; ++jj) {
      float4 v = rok ? *(const float4*)(bp + kc + jj * 4)
                     : make_float4(0.f, 0.f, 0.f, 0.f);
      const int kk = spart * 16 + jj * 4;
      Bs[kk + 0][srow] = v.x; Bs[kk + 1][srow] = v.y;
      Bs[kk + 2][srow] = v.z; Bs[kk + 3][srow] = v.w;
    }
    {
      float4 v = *(const float4*)(cp + kc);
      Cs[ck + 0][cb] = v.x; Cs[ck + 1][cb] = v.y;
      Cs[ck + 2][cb] = v.z; Cs[ck + 3][cb] = v.w;
    }
    __syncthreads();
#pragma unroll
    for (int kk = 0; kk < 32; ++kk) {
      float4 av = *(const float4*)&Bs[kk][ty * 4];
      float4 bv = *(const float4*)&Cs[kk][tx * 4];
      float a4[4] = {av.x, av.y, av.z, av.w};
      float b4[4] = {bv.x, bv.y, bv.z, bv.w};
#pragma unroll
      for (int i = 0; i < 4; ++i)
#pragma unroll
        for (int j = 0; j < 4; ++j) acc[i][j] += a4[i] * b4[j];
    }
  }
  const int n = n0 + ty * 4;
#pragma unroll
  for (int j = 0; j < 4; ++j) {
    const int b = tx * 4 + j;
    float4 o = make_float4(acc[0][j], acc[1][j], acc[2][j], acc[3][j]);
    if (n + 3 < NB) {
      *(float4*)(sims + (size_t)b * NB + n) = o;
    } else {
      float oo[4] = {o.x, o.y, o.z, o.w};
      for (int i = 0; i < 4; ++i)
        if (n + i < NB) sims[(size_t)b * NB + n + i] = oo[i];
    }
  }
}

// ===================== top-K stage 1: per-(row,chunk) top-16 ====================
__global__ __launch_bounds__(256) void topk_stage1(const float* __restrict__ sims,
                                                   float* __restrict__ cv,
                                                   int* __restrict__ ci) {
  __shared__ float ss[4096];
  __shared__ int si[4096];
  __shared__ float wv[4];
  __shared__ int wi[4];
  const int chunk = blockIdx.x, b = blockIdx.y, tid = threadIdx.x;
  const int start = chunk * (NB / TKCH), end = start + (NB / TKCH);
  float ls[16]; int li[16];
#pragma unroll
  for (int i = 0; i < 16; ++i) { ls[i] = -FLT_MAX; li[i] = 0x7fffffff; }
  const float* row = sims + (size_t)b * NB;
  float lmin = -FLT_MAX;
  for (int n = start + tid; n < end; n += 256) {
    float v = row[n];
    if (v > lmin) {
      int p = 15;
      while (p > 0 && ls[p - 1] < v) { ls[p] = ls[p - 1]; li[p] = li[p - 1]; --p; }
      ls[p] = v; li[p] = n;
      lmin = ls[15];
    }
  }
#pragma unroll
  for (int i = 0; i < 16; ++i) { ss[i * 256 + tid] = ls[i]; si[i * 256 + tid] = li[i]; }
  __syncthreads();
  for (int round = 0; round < 16; ++round) {
    float bv = -FLT_MAX; int bi = 0x7fffffff;
#pragma unroll
    for (int i = 0; i < 16; ++i) {
      float v = ss[i * 256 + tid]; int ix = si[i * 256 + tid];
      if (v > bv || (v == bv && ix < bi)) { bv = v; bi = ix; }
    }
#pragma unroll
    for (int s = 32; s; s >>= 1) {
      float ov = __shfl_down(bv, s); int oi = __shfl_down(bi, s);
      if (ov > bv || (ov == bv && oi < bi)) { bv = ov; bi = oi; }
    }
    if ((tid & 63) == 0) { wv[tid >> 6] = bv; wi[tid >> 6] = bi; }
    __syncthreads();
    if (tid == 0) {
      bv = wv[0]; bi = wi[0];
      for (int w = 1; w < 4; ++w)
        if (wv[w] > bv || (wv[w] == bv && wi[w] < bi)) { bv = wv[w]; bi = wi[w]; }
      cv[(b * TKCH + chunk) * 16 + round] = bv;
      ci[(b * TKCH + chunk) * 16 + round] = bi;
      wi[0] = bi;
    }
    __syncthreads();
    bi = wi[0];
#pragma unroll
    for (int i = 0; i < 16; ++i)
      if (si[i * 256 + tid] == bi) ss[i * 256 + tid] = -FLT_MAX;
    __syncthreads();
  }
}

// ===================== top-K stage 2: 256 candidates -> top-16 ==================
__global__ __launch_bounds__(256) void topk_stage2(const float* __restrict__ cv,
                                                   const int* __restrict__ ci,
                                                   float* __restrict__ tks,
                                                   int* __restrict__ tki) {
  __shared__ float wv[4];
  __shared__ int wi[4];
  __shared__ int bw;
  const int b = blockIdx.x, tid = threadIdx.x;
  float val = cv[b * 256 + tid];
  int idx = ci[b * 256 + tid];
  for (int round = 0; round < 16; ++round) {
    float bv = val; int bi = idx;
#pragma unroll
    for (int s = 1; s < 64; s <<= 1) {
      float ov = __shfl_xor(bv, s); int oi = __shfl_xor(bi, s);
      if (ov > bv || (ov == bv && oi < bi)) { bv = ov; bi = oi; }
    }
    if ((tid & 63) == 0) { wv[tid >> 6] = bv; wi[tid >> 6] = bi; }
    __syncthreads();
    if (tid == 0) {
      bv = wv[0]; bi = wi[0];
      for (int w = 1; w < 4; ++w)
        if (wv[w] > bv || (wv[w] == bv && wi[w] < bi)) { bv = wv[w]; bi = wi[w]; }
      tks[b * 16 + round] = bv; tki[b * 16 + round] = bi;
      bw = bi;
    }
    __syncthreads();
    if (idx == bw) val = -FLT_MAX;
  }
}

// ===================== small copy/assembly kernels ==============================
__global__ void sem_kernel(const float* __restrict__ bank, const float* __restrict__ tks,
                           const int* __restrict__ tki, float* __restrict__ sem) {
  int slot = blockIdx.x;
  float s = tks[slot]; int idx = tki[slot];
  for (int i = threadIdx.x; i < 768; i += 256)
    sem[(size_t)slot * 768 + i] = bank[(size_t)idx * 768 + i] * s;
}

__global__ void build_hist_in(const float* __restrict__ img, const float* __restrict__ pr,
                              float* __restrict__ out) {
  int r = blockIdx.x;
  for (int i = threadIdx.x; i < 777; i += 256)
    out[(size_t)r * 777 + i] = (i < 768) ? img[(size_t)r * 768 + i] : pr[r * 9 + (i - 768)];
}

__global__ void build_img_in(const float* __restrict__ goal, const float* __restrict__ sub,
                             const float* __restrict__ bea, const float* __restrict__ sem,
                             float* __restrict__ out) {
  int r = blockIdx.x;
  const float* src = (r < 32) ? goal + (size_t)r * 768
                   : (r < 64) ? sub + (size_t)(r - 32) * 768
                   : (r < 96) ? bea + (size_t)(r - 64) * 768
                              : sem + (size_t)(r - 96) * 768;
  for (int i = threadIdx.x; i < 768; i += 256) out[(size_t)r * 768 + i] = src[i];
}

__global__ void assemble_x(const float* __restrict__ th, const float* __restrict__ ti,
                           const float* __restrict__ tp, const float* __restrict__ plan,
                           float* __restrict__ x) {
  int r = blockIdx.x;
  int b = r / SEQ, tok = r - b * SEQ;
  const float* src;
  if (tok == 0) src = plan;
  else if (tok <= 16) src = th + (size_t)(b * 16 + tok - 1) * 1024;
  else if (tok <= 19) src = ti + (size_t)((tok - 17) * 32 + b) * 1024;
  else if (tok <= 35) src = ti + (size_t)(96 + b * 16 + (tok - 20)) * 1024;
  else src = tp + (size_t)b * 1024;
  for (int i = threadIdx.x; i < 1024; i += 256) x[(size_t)r * 1024 + i] = src[i];
}

__global__ void build_ref(const float* __restrict__ ps, const float* __restrict__ anc,
                          float* __restrict__ ref) {
  int b = blockIdx.x;
  for (int i = threadIdx.x; i < 1027; i += 256)
    ref[(size_t)b * 1027 + i] = (i < 1024) ? ps[(size_t)b * 1024 + i] : anc[b * 3 + (i - 1024)];
}

// ===================== layernorm ===============================================
__device__ __forceinline__ float block_sum256(float v, float* red) {
#pragma unroll
  for (int s = 32; s; s >>= 1) v += __shfl_down(v, s);
  if ((threadIdx.x & 63) == 0) red[threadIdx.x >> 6] = v;
  __syncthreads();
  float tot = red[0] + red[1] + red[2] + red[3];
  __syncthreads();
  return tot;
}

__global__ __launch_bounds__(256) void ln_kernel(const float* __restrict__ in, int in_stride,
                                                 float* __restrict__ out,
                                                 const float* __restrict__ g,
                                                 const float* __restrict__ bt) {
  __shared__ float red[4];
  const float* xr = in + (size_t)blockIdx.x * in_stride;
  const int tid = threadIdx.x;
  float v[4];
#pragma unroll
  for (int i = 0; i < 4; ++i) v[i] = xr[tid + 256 * i];
  float mean = block_sum256(v[0] + v[1] + v[2] + v[3], red) * (1.f / 1024.f);
  float sq = 0.f;
#pragma unroll
  for (int i = 0; i < 4; ++i) { float d = v[i] - mean; sq += d * d; }
  float var = block_sum256(sq, red) * (1.f / 1024.f);
  float inv = rsqrtf(var + 1e-5f);
  float* orow = out + (size_t)blockIdx.x * 1024;
#pragma unroll
  for (int i = 0; i < 4; ++i) {
    int c = tid + 256 * i;
    orow[c] = (v[i] - mean) * inv * g[c] + bt[c];
  }
}

// ===================== generic fp32 GEMM (small shapes only) ====================
__global__ __launch_bounds__(256) void gemm_f32(const float* __restrict__ A, int lda,
                                                const float* __restrict__ W, int ldw,
                                                const float* __restrict__ bias,
                                                float* __restrict__ C, int ldc,
                                                int M, int N, int K, int acc_flag) {
  __shared__ float As[32][68];
  __shared__ float Ws[32][68];
  const int tid = threadIdx.x;
  const int tx = tid & 15, ty = tid >> 4;
  const int bm = blockIdx.x * 64, bn = blockIdx.y * 64;
  float acc[4][4] = {{0.f, 0.f, 0.f, 0.f}, {0.f, 0.f, 0.f, 0.f},
                     {0.f, 0.f, 0.f, 0.f}, {0.f, 0.f, 0.f, 0.f}};
  for (int kc = 0; kc < K; kc += 32) {
    for (int i = tid; i < 64 * 32; i += 256) {
      int r = i >> 5, kk = i & 31;
      int gk = kc + kk;
      int gm = bm + r, gn = bn + r;
      As[kk][r] = (gm < M && gk < K) ? A[(size_t)gm * lda + gk] : 0.f;
      Ws[kk][r] = (gn < N && gk < K) ? W[(size_t)gn * ldw + gk] : 0.f;
    }
    __syncthreads();
#pragma unroll
    for (int kk = 0; kk < 32; ++kk) {
      float4 av = *(const float4*)&As[kk][ty * 4];
      float4 bv = *(const float4*)&Ws[kk][tx * 4];
      float a4[4] = {av.x, av.y, av.z, av.w};
      float b4[4] = {bv.x, bv.y, bv.z, bv.w};
#pragma unroll
      for (int i = 0; i < 4; ++i)
#pragma unroll
        for (int j = 0; j < 4; ++j) acc[i][j] += a4[i] * b4[j];
    }
    __syncthreads();
  }
#pragma unroll
  for (int i = 0; i < 4; ++i) {
    int gm = bm + ty * 4 + i;
    if (gm >= M) continue;
#pragma unroll
    for (int j = 0; j < 4; ++j) {
      int gn = bn + tx * 4 + j;
      if (gn >= N) continue;
      float o = acc[i][j] + bias[gn];
      size_t off = (size_t)gm * ldc + gn;
      if (acc_flag) o += C[off];
      C[off] = o;
    }
  }
}

// ===================== LoRA (multi: blockIdx.y selects among up to 3) ===========
__global__ __launch_bounds__(64) void lora_down(const float* __restrict__ h,
                                                const float* __restrict__ A0,
                                                const float* __restrict__ A1,
                                                const float* __restrict__ A2,
                                                float* __restrict__ lt, int K) {
  const int m = blockIdx.x, z = blockIdx.y, lane = threadIdx.x;
  const float* A = (z == 0) ? A0 : (z == 1) ? A1 : A2;
  float p[8] = {0.f, 0.f, 0.f, 0.f, 0.f, 0.f, 0.f, 0.f};
  for (int kk = lane; kk < K; kk += 64) {
    float hv = h[(size_t)m * K + kk];
#pragma unroll
    for (int r = 0; r < 8; ++r) p[r] += hv * A[r * K + kk];
  }
#pragma unroll
  for (int s = 1; s < 64; s <<= 1) {
#pragma unroll
    for (int r = 0; r < 8; ++r) p[r] += __shfl_xor(p[r], s);
  }
#pragma unroll
  for (int r = 0; r < 8; ++r)
    if (lane == r) lt[((size_t)z * NTOK + m) * 8 + r] = p[r];
}

__global__ __launch_bounds__(256) void lora_up(const float* __restrict__ lt,
                                               const float* __restrict__ B0,
                                               const float* __restrict__ B1,
                                               const float* __restrict__ B2,
                                               float* __restrict__ C, size_t czstride,
                                               int N, int total, int gelu_flag) {
  int id = blockIdx.x * 256 + threadIdx.x;
  if (id >= total) return;
  const int z = blockIdx.y;
  const float* Bm = (z == 0) ? B0 : (z == 1) ? B1 : B2;
  C += (size_t)z * czstride;
  int m = id / N, n = id - m * N;
  const float* t = lt + ((size_t)z * NTOK + m) * 8;
  const float* bp = Bm + (size_t)n * 8;
  float s = t[0] * bp[0] + t[1] * bp[1] + t[2] * bp[2] + t[3] * bp[3] +
            t[4] * bp[4] + t[5] * bp[5] + t[6] * bp[6] + t[7] * bp[7];
  float o = C[id] + s;
  C[id] = gelu_flag ? gelu_f(o) : o;
}

// ===================== attention ================================================
__global__ __launch_bounds__(256) void attn_kernel(const float* __restrict__ q,
                                                   const float* __restrict__ k,
                                                   const float* __restrict__ v,
                                                   float* __restrict__ ao) {
  __shared__ float qs[SEQ * 64], ks[SEQ * 64], vs[SEQ * 64], sc[SEQ * 40];
  const int head = blockIdx.x, b = blockIdx.y, tid = threadIdx.x;
  const size_t base = ((size_t)b * SEQ) * 1024 + head * 64;
  for (int i = tid; i < SEQ * 64; i += 256) {
    int s = i >> 6, d = i & 63;
    size_t off = base + (size_t)s * 1024 + d;
    qs[i] = q[off]; ks[i] = k[off]; vs[i] = v[off];
  }
  __syncthreads();
  for (int p = tid; p < SEQ * SEQ; p += 256) {
    int s = p / SEQ, t = p - s * SEQ;
    float acc = 0.f;
#pragma unroll 16
    for (int d = 0; d < 64; ++d) acc += qs[s * 64 + d] * ks[t * 64 + d];
    sc[s * 40 + t] = acc * 0.125f;
  }
  __syncthreads();
  if (tid < SEQ) {
    float m = -FLT_MAX;
    for (int t = 0; t < SEQ; ++t) m = fmaxf(m, sc[tid * 40 + t]);
    float sum = 0.f;
    for (int t = 0; t < SEQ; ++t) { float e = expf(sc[tid * 40 + t] - m); sc[tid * 40 + t] = e; sum += e; }
    float inv = 1.f / sum;
    for (int t = 0; t < SEQ; ++t) sc[tid * 40 + t] *= inv;
  }
  __syncthreads();
  for (int i = tid; i < SEQ * 64; i += 256) {
    int s = i >> 6, d = i & 63;
    float acc = 0.f;
    for (int t = 0; t < SEQ; ++t) acc += sc[s * 40 + t] * vs[t * 64 + d];
    ao[base + (size_t)s * 1024 + d] = acc;
  }
}

// ===================== gelu (exact, erf) ========================================
__global__ void gelu_kernel(float* __restrict__ x, int n) {
  int i = blockIdx.x * blockDim.x + threadIdx.x;
  if (i < n) x[i] = gelu_f(x[i]);
}

// ===================== host =====================================================
extern "C" void kernel_launch(void* const* d_in, const int* in_sizes, int n_in,
                              void* d_out, int out_size, void* d_ws, size_t ws_size,
                              hipStream_t stream) {
  const float* hist_img = (const float*)d_in[0];
  const float* cur      = (const float*)d_in[1];
  const float* goal     = (const float*)d_in[2];
  const float* sub      = (const float*)d_in[3];
  const float* bea      = (const float*)d_in[4];
  const float* hist_pr  = (const float*)d_in[5];
  const float* prop     = (const float*)d_in[6];
  const float* bank     = (const float*)d_in[7];
  const float* hpW = (const float*)d_in[8];  const float* hpb = (const float*)d_in[9];
  const float* ipW = (const float*)d_in[10]; const float* ipb = (const float*)d_in[11];
  const float* ppW = (const float*)d_in[12]; const float* ppb = (const float*)d_in[13];
  const float* plan = (const float*)d_in[14];
  const float* ln1g = (const float*)d_in[15]; const float* ln1b = (const float*)d_in[16];
  const float* ln2g = (const float*)d_in[17]; const float* ln2b = (const float*)d_in[18];
  const float* qW = (const float*)d_in[19]; const float* qA = (const float*)d_in[20];
  const float* qB = (const float*)d_in[21]; const float* qb = (const float*)d_in[22];
  const float* kW = (const float*)d_in[23]; const float* kA = (const float*)d_in[24];
  const float* kB = (const float*)d_in[25]; const float* kb = (const float*)d_in[26];
  const float* vW = (const float*)d_in[27]; const float* vA = (const float*)d_in[28];
  const float* vB = (const float*)d_in[29]; const float* vb = (const float*)d_in[30];
  const float* oW = (const float*)d_in[31]; const float* oA = (const float*)d_in[32];
  const float* oB = (const float*)d_in[33]; const float* ob = (const float*)d_in[34];
  const float* f1W = (const float*)d_in[35]; const float* f1A = (const float*)d_in[36];
  const float* f1B = (const float*)d_in[37]; const float* f1b = (const float*)d_in[38];
  const float* f2W = (const float*)d_in[39]; const float* f2A = (const float*)d_in[40];
  const float* f2B = (const float*)d_in[41]; const float* f2b = (const float*)d_in[42];
  const float* flng = (const float*)d_in[43]; const float* flnb = (const float*)d_in[44];
  const float* ahW1 = (const float*)d_in[45]; const float* ahb1 = (const float*)d_in[46];
  const float* ahW2 = (const float*)d_in[47]; const float* ahb2 = (const float*)d_in[48];
  const float* rhW1 = (const float*)d_in[49]; const float* rhb1 = (const float*)d_in[50];
  const float* rhW2 = (const float*)d_in[51]; const float* rhb2 = (const float*)d_in[52];
  const float* shW = (const float*)d_in[53]; const float* shb = (const float*)d_in[54];
  float* out = (float*)d_out;

  float* ws  = (float*)d_ws;
  float* F1O = ws;
  float* SIMS = ws;
  float* X   = F1O + (size_t)NTOK * 4096;
  float* Hb  = X  + (size_t)NTOK * 1024;
  float* Qb  = Hb + (size_t)NTOK * 1024;
  float* Kb  = Qb + (size_t)NTOK * 1024;
  float* Vb  = Kb + (size_t)NTOK * 1024;
  float* AOb = Vb + (size_t)NTOK * 1024;
  float* LT  = AOb + (size_t)NTOK * 1024;      // 3*NTOK*8
  float* SEM = LT + (size_t)3 * NTOK * 8;      // 512*768
  float* HIN = SEM + (size_t)512 * 768;        // 512*777
  float* TKS = HIN + (size_t)512 * 777;        // 512
  int*   TKI = (int*)(TKS + 512);              // 512
  float* PS  = TKS + 1024;                     // 32*1024
  float* HH  = PS + 32 * 1024;                 // 32*1024
  float* REF = HH + 32 * 1024;                 // 32*1027
  float* CV  = REF + 32 * 1027;                // 32*256
  int*   CI  = (int*)(CV + 32 * 256);          // 32*256
  short* WB  = (short*)(CI + 32 * 256);        // 12*1048576 shorts = 25.2 MB

  const size_t czs = (size_t)NTOK * 1024;
  const size_t WM = 1048576;  // shorts per 1024x1024 weight

  auto gemmb1 = [&](const float* A, int lda, const float* W, int ldw, const float* bias,
                    float* C, int ldc, int M, int N, int K, int accf) {
    dim3 g((M + 127) / 128, N / 128, 1);
    gemm_bf16<<<g, 256, 0, stream>>>(A, lda, W, ldw, bias, C, ldc, M, N, K, accf);
  };
  auto gemm = [&](const float* A, int lda, const float* W, int ldw, const float* bias,
                  float* C, int ldc, int M, int N, int K, int accf) {
    dim3 g((M + 63) / 64, (N + 63) / 64);
    gemm_f32<<<g, 256, 0, stream>>>(A, lda, W, ldw, bias, C, ldc, M, N, K, accf);
  };

  // ---- retrieval ----
  sims_kernel<<<(NB + 127) / 128, 256, 0, stream>>>(cur, bank, SIMS);
  topk_stage1<<<dim3(TKCH, 32), 256, 0, stream>>>(SIMS, CV, CI);
  topk_stage2<<<32, 256, 0, stream>>>(CV, CI, TKS, TKI);
  sem_kernel<<<512, 256, 0, stream>>>(bank, TKS, TKI, SEM);

  // ---- token embedding ----
  build_hist_in<<<512, 256, 0, stream>>>(hist_img, hist_pr, HIN);
  build_img_in<<<608, 256, 0, stream>>>(goal, sub, bea, SEM, AOb);
  gemmb1(HIN, 777, hpW, 777, hpb, Qb, 1024, 512, 1024, 777, 0);
  gemmb1(AOb, 768, ipW, 768, ipb, Kb, 1024, 608, 1024, 768, 0);
  gemm(prop, 9, ppW, 9, ppb, Vb, 1024, 32, 1024, 9, 0);
  assemble_x<<<NTOK, 256, 0, stream>>>(Qb, Kb, Vb, plan, X);

  // ---- transformer layers ----
  const int upb = (NTOK * 1024 + 255) / 256;
  const int mblk = (NTOK + 127) / 128;  // 10
  for (int l = 0; l < 6; ++l) {
    const size_t wO = (size_t)l * 1024 * 1024, aO = (size_t)l * 8 * 1024,
                 bO = (size_t)l * 1024 * 8, biO = (size_t)l * 1024;
    const size_t w4O = (size_t)l * 4096 * 1024, a4O = (size_t)l * 8 * 4096,
                 b4O = (size_t)l * 4096 * 8, bi4O = (size_t)l * 4096;
    // convert this layer's weights to tiled bf16 (q,k,v,o,f1,f2)
    wconv<<<1536, 256, 0, stream>>>(qW + wO, kW + wO, vW + wO, oW + wO,
                                    f1W + w4O, f2W + w4O, WB);
    ln_kernel<<<NTOK, 256, 0, stream>>>(X, 1024, Hb, ln1g + biO, ln1b + biO);
    // fused QKV
    gemm_bt<<<dim3(mblk, 8, 3), 256, 0, stream>>>(
        Hb, 1024, WB, WM, qb + biO, kb + biO, vb + biO,
        Qb, czs, 1024, NTOK, 1024, 0);
    lora_down<<<dim3(NTOK, 3), 64, 0, stream>>>(Hb, qA + aO, kA + aO, vA + aO, LT, 1024);
    lora_up<<<dim3(upb, 3), 256, 0, stream>>>(LT, qB + bO, kB + bO, vB + bO,
                                              Qb, czs, 1024, NTOK * 1024, 0);
    attn_kernel<<<dim3(16, 32), 256, 0, stream>>>(Qb, Kb, Vb, AOb);
    gemm_bt<<<dim3(mblk, 8, 1), 256, 0, stream>>>(
        AOb, 1024, WB + 3 * WM, 0, ob + biO, ob + biO, ob + biO,
        X, 0, 1024, NTOK, 1024, 1);
    lora_down<<<dim3(NTOK, 1), 64, 0, stream>>>(AOb, oA + aO, oA + aO, oA + aO, LT, 1024);
    lora_up<<<dim3(upb, 1), 256, 0, stream>>>(LT, oB + bO, oB + bO, oB + bO,
                                              X, 0, 1024, NTOK * 1024, 0);
    ln_kernel<<<NTOK, 256, 0, stream>>>(X, 1024, Hb, ln2g + biO, ln2b + biO);
    gemm_bt<<<dim3(mblk, 32, 1), 256, 0, stream>>>(
        Hb, 1024, WB + 4 * WM, 0, f1b + bi4O, f1b + bi4O, f1b + bi4O,
        F1O, 0, 4096, NTOK, 1024, 0);
    lora_down<<<dim3(NTOK, 1), 64, 0, stream>>>(Hb, f1A + aO, f1A + aO, f1A + aO, LT, 1024);
    lora_up<<<dim3((NTOK * 4096 + 255) / 256, 1), 256, 0, stream>>>(
        LT, f1B + b4O, f1B + b4O, f1B + b4O, F1O, 0, 4096, NTOK * 4096, 1);  // +gelu
    gemm_bt<<<dim3(mblk, 8, 1), 256, 0, stream>>>(
        F1O, 4096, WB + 8 * WM, 0, f2b + biO, f2b + biO, f2b + biO,
        X, 0, 1024, NTOK, 4096, 1);
    lora_down<<<dim3(NTOK, 1), 64, 0, stream>>>(F1O, f2A + a4O, f2A + a4O, f2A + a4O, LT, 4096);
    lora_up<<<dim3(upb, 1), 256, 0, stream>>>(LT, f2B + bO, f2B + bO, f2B + bO,
                                              X, 0, 1024, NTOK * 1024, 0);
  }

  // ---- heads ----
  ln_kernel<<<32, 256, 0, stream>>>(X, SEQ * 1024, PS, flng, flnb);
  gemm(PS, 1024, ahW1, 1024, ahb1, HH, 1024, 32, 1024, 1024, 0);
  gelu_kernel<<<(32 * 1024 + 255) / 256, 256, 0, stream>>>(HH, 32 * 1024);
  gemm(HH, 1024, ahW2, 1024, ahb2, out, 3, 32, 3, 1024, 0);
  build_ref<<<32, 256, 0, stream>>>(PS, out, REF);
  gemm(REF, 1027, rhW1, 1027, rhb1, HH, 1024, 32, 1024, 1027, 0);
  gelu_kernel<<<(32 * 1024 + 255) / 256, 256, 0, stream>>>(HH, 32 * 1024);
  gemm(HH, 1024, rhW2, 1024, rhb2, out + 96, 24, 32, 24, 1024, 0);
  gemm(PS, 1024, shW, 1024, shb, out + 864, 1, 32, 1, 1024, 0);
}